// Round 1
// baseline (549.976 us; speedup 1.0000x reference)
//
#include <hip/hip_runtime.h>
#include <math.h>

#define L 1024
#define D 64
#define H 8
#define B 8

// ws layout (float offsets)
#define WS_PART 0                 // 8*1024*5*15 = 614400
#define WS_MU   614400            // 8*1024*5    = 40960
#define WS_Q2   655360            // 8*1024*25   = 204800
#define WS_KEFF 860160            // 8*8*1024*64 = 4194304
#define WS_SCAL_BYTES 20217856    // 2 doubles (lp_sum, ce_sum)

// ---------------- Kernel 1: conv1 partials ----------------
// part[bi][li][jj][nc*3+t] = sum_c K_unfold[bi,c,li,jj] * w_proj_k[nc,c,t]
__global__ __launch_bounds__(64) void k_part(const float* __restrict__ K,
                                             const float* __restrict__ wpk,
                                             float* __restrict__ part) {
  const int lane = threadIdx.x;
  const int lq = blockIdx.x;   // 0..15  (li >> 6)
  const int jj = blockIdx.y;   // 0..4
  const int bi = blockIdx.z;   // 0..7
  __shared__ float w_s[512 * 16];
  for (int i = lane; i < 512 * 15; i += 64) {
    int c = i / 15, f = i % 15;
    int nc = f / 3, t = f % 3;
    w_s[c * 16 + f] = wpk[(nc * 512 + c) * 3 + t];
  }
  __syncthreads();
  float acc[15];
#pragma unroll
  for (int f = 0; f < 15; ++f) acc[f] = 0.f;
  if (bi + jj >= 5) {
    const float* Kb = K + (size_t)(bi + jj - 4) * (H * L * D);
#pragma unroll 4
    for (int c = 0; c < 512; ++c) {
      int hh = c >> 6;
      int li2 = ((c & 63) << 4) + lq;
      float val = Kb[(hh * L + li2) * D + lane];
      const float* wr = &w_s[c * 16];
#pragma unroll
      for (int f = 0; f < 15; ++f) acc[f] = fmaf(val, wr[f], acc[f]);
    }
  }
  int li = (lq << 6) + lane;
  float* dst = part + ((size_t)(bi * L + li) * 5 + jj) * 15;
#pragma unroll
  for (int f = 0; f < 15; ++f) dst[f] = acc[f];
}

// ---------------- Kernel 2: per-(bi,li) chain ----------------
__global__ __launch_bounds__(256) void k_chain(const float* __restrict__ part,
    const float* __restrict__ b_pk, const float* __restrict__ w_ck,
    const float* __restrict__ b_ck, const float* __restrict__ w_cq,
    const float* __restrict__ b_cq, float* __restrict__ mu_out,
    float* __restrict__ q2_out, double* __restrict__ dsc) {
  int g = blockIdx.x * 256 + threadIdx.x;  // 0..8191 == bi*1024+li
  const float* p = part + (size_t)g * 75;
  float ckp[5][5];
#pragma unroll
  for (int j = 0; j < 5; ++j) {
#pragma unroll
    for (int nc = 0; nc < 5; ++nc) {
      float s = b_pk[nc];
#pragma unroll
      for (int t = 0; t < 3; ++t) {
        int w = j + t - 1;
        if (w >= 0 && w < 5) s += p[w * 15 + nc * 3 + t];
      }
      ckp[j][nc] = fmaxf(s, 0.f);
    }
  }
  float cq[5][5], ck[5][5];
  float lp_sum = 0.f;
#pragma unroll
  for (int j = 0; j < 5; ++j) {
    float vk[5], vq[5];
#pragma unroll
    for (int m = 0; m < 5; ++m) {
      float sk = b_ck[m], sq = b_cq[m];
#pragma unroll
      for (int n = 0; n < 5; ++n) {
        sk = fmaf(ckp[j][n], w_ck[m * 5 + n], sk);
        sq = fmaf(ckp[j][n], w_cq[m * 5 + n], sq);
      }
      vk[m] = sk; vq[m] = sq;
    }
    float mk = vk[0], mq = vq[0];
#pragma unroll
    for (int m = 1; m < 5; ++m) { mk = fmaxf(mk, vk[m]); mq = fmaxf(mq, vq[m]); }
    float sk = 0.f, sq = 0.f;
#pragma unroll
    for (int m = 0; m < 5; ++m) {
      vk[m] = expf(vk[m] - mk); sk += vk[m];
      vq[m] = expf(vq[m] - mq); sq += vq[m];
    }
    float rk = 1.f / sk, rq = 1.f / sq;
    float mu = 0.f, x = 0.f;
#pragma unroll
    for (int m = 0; m < 5; ++m) {
      ck[j][m] = vk[m] * rk; cq[j][m] = vq[m] * rq;
      mu += cq[j][m]; x += ck[j][m];
    }
    mu *= 0.2f; x *= 0.2f;
    float var = 0.f;
#pragma unroll
    for (int m = 0; m < 5; ++m) { float d0 = cq[j][m] - mu; var += d0 * d0; }
    var *= 0.25f;  // ddof=1
    float sg = log1pf(expf(sqrtf(var)));   // softplus(std)
    float z = (x - mu) / sg;
    lp_sum += -0.5f * z * z - logf(sg) - 0.91893853320467274f;
    mu_out[(size_t)g * 5 + j] = mu;
  }
  // masked triangular cluster attention -> q2
  float* q2p = q2_out + (size_t)g * 25;
#pragma unroll
  for (int pp = 0; pp < 5; ++pp) {
    float sc[5]; float mx = -3.0e38f;
    for (int u2 = 0; u2 <= pp; ++u2) {
      float d0 = 0.f;
#pragma unroll
      for (int c = 0; c < 5; ++c) d0 = fmaf(cq[pp][c], ck[u2][c], d0);
      sc[u2] = d0 * 0.2f;
      mx = fmaxf(mx, sc[u2]);
    }
    float den = 0.f;
    for (int u2 = 0; u2 <= pp; ++u2) { sc[u2] = expf(sc[u2] - mx); den += sc[u2]; }
    float rd = 1.f / den;
    float q2v[5] = {0.f, 0.f, 0.f, 0.f, 0.f};
    for (int u2 = 0; u2 <= pp; ++u2) {
      float a = sc[u2] * rd;
#pragma unroll
      for (int c = 0; c < 5; ++c) q2v[c] = fmaf(a, cq[u2][c], q2v[c]);
    }
#pragma unroll
    for (int c = 0; c < 5; ++c) q2p[pp * 5 + c] = q2v[c];
  }
  // reduce log_prob sum
  for (int off = 1; off < 64; off <<= 1) lp_sum += __shfl_xor(lp_sum, off, 64);
  __shared__ float wsum[4];
  int tid = threadIdx.x;
  if ((tid & 63) == 0) wsum[tid >> 6] = lp_sum;
  __syncthreads();
  if (tid == 0) atomicAdd(dsc, (double)(wsum[0] + wsum[1] + wsum[2] + wsum[3]));
}

// ---------------- Kernel 3: CE over l axis ----------------
__global__ __launch_bounds__(256) void k_ce(const float* __restrict__ mu,
                                            double* __restrict__ dsc) {
  int bi = blockIdx.x / 5, u = blockIdx.x % 5;
  int tid = threadIdx.x;
  const float* base = mu + (size_t)bi * L * 5 + u;
  float v[4];
#pragma unroll
  for (int k = 0; k < 4; ++k) v[k] = base[(tid + 256 * k) * 5];
  float mx = fmaxf(fmaxf(v[0], v[1]), fmaxf(v[2], v[3]));
  for (int off = 1; off < 64; off <<= 1) mx = fmaxf(mx, __shfl_xor(mx, off, 64));
  __shared__ float sh[4];
  if ((tid & 63) == 0) sh[tid >> 6] = mx;
  __syncthreads();
  mx = fmaxf(fmaxf(sh[0], sh[1]), fmaxf(sh[2], sh[3]));
  __syncthreads();
  float se = 0.f;
#pragma unroll
  for (int k = 0; k < 4; ++k) se += expf(v[k] - mx);
  for (int off = 1; off < 64; off <<= 1) se += __shfl_xor(se, off, 64);
  if ((tid & 63) == 0) sh[tid >> 6] = se;
  __syncthreads();
  float lse = mx + logf(sh[0] + sh[1] + sh[2] + sh[3]);
  __syncthreads();
  float part = 0.f;
#pragma unroll
  for (int k = 0; k < 4; ++k) part += v[k] * (v[k] - lse);
  for (int off = 1; off < 64; off <<= 1) part += __shfl_xor(part, off, 64);
  if ((tid & 63) == 0) sh[tid >> 6] = part;
  __syncthreads();
  if (tid == 0) atomicAdd(dsc + 1, (double)(sh[0] + sh[1] + sh[2] + sh[3]));
}

// ---------------- Kernel 4: back-projection + cluster sum -> Keff ----------------
__global__ __launch_bounds__(256) void k_keff(const float* __restrict__ q2,
    const float* __restrict__ wb, const float* __restrict__ bb,
    float* __restrict__ keff) {
  int g = blockIdx.x * 256 + threadIdx.x;  // over b*h*l*d
  int bi = g >> 19;
  int r = g & 524287;
  int hh = r >> 16;
  int li2 = (r >> 6) & 1023;
  int dd = r & 63;
  int base = hh * 327680 + li2 * 64 + dd;
  const float* q2b = q2 + (size_t)bi * L * 25;
  float sum = 0.f;
#pragma unroll
  for (int cc = 0; cc < 5; ++cc) {
    int flat = base + cc * 65536;
    int co = (int)((unsigned)flat / 5120u);
    int rem = flat - co * 5120;
    int li = (int)((unsigned)rem / 5u);
    int j = rem - li * 5;
    const float* qr = q2b + li * 25;
    const float* wr = wb + co * 15;
    float s = bb[co];
#pragma unroll
    for (int t = 0; t < 3; ++t) {
      int w = j + t - 1;
      if (w >= 0 && w < 5) {
#pragma unroll
        for (int c = 0; c < 5; ++c) s = fmaf(qr[w * 5 + c], wr[c * 3 + t], s);
      }
    }
    sum += fmaxf(s, 0.f);
  }
  keff[g] = sum;
}

// ---------------- Kernel 5: f32 flash attention ----------------
__global__ __launch_bounds__(256) void k_attn(const float* __restrict__ Q,
    const float* __restrict__ Kf, const float* __restrict__ V,
    float* __restrict__ Out) {
  __shared__ float Qst[64][68];  // [kk][r]  (transposed)
  __shared__ float KP[64][68];   // Kst [kk][c] during S; Ps [r][c] during PV
  __shared__ float Vs[64][68];   // [c][dd]
  const int tid = threadIdx.x;
  const int ty = tid >> 4, tx = tid & 15;
  const int bh = blockIdx.y;
  const int q0 = blockIdx.x << 6;
  const float* Qb = Q + ((size_t)bh * L + q0) * D;
  const float* Kb = Kf + (size_t)bh * L * D;
  const float* Vb = V + (size_t)bh * L * D;
  {
    int r = tid >> 2, c0 = (tid & 3) << 4;
#pragma unroll
    for (int ch = 0; ch < 4; ++ch) {
      float4 q = *(const float4*)(Qb + r * 64 + c0 + ch * 4);
      Qst[c0 + ch * 4 + 0][r] = q.x;
      Qst[c0 + ch * 4 + 1][r] = q.y;
      Qst[c0 + ch * 4 + 2][r] = q.z;
      Qst[c0 + ch * 4 + 3][r] = q.w;
    }
  }
  float O[4][4] = {};
  float m[4], l[4];
#pragma unroll
  for (int i = 0; i < 4; ++i) { m[i] = -3.0e38f; l[i] = 0.f; }
  for (int kt = 0; kt < 16; ++kt) {
    __syncthreads();
    {
      int r = tid >> 2, c0 = (tid & 3) << 4;
      const float* Krow = Kb + (kt * 64 + r) * 64 + c0;
      const float* Vrow = Vb + (kt * 64 + r) * 64 + c0;
#pragma unroll
      for (int ch = 0; ch < 4; ++ch) {
        float4 kq = *(const float4*)(Krow + ch * 4);
        KP[c0 + ch * 4 + 0][r] = kq.x;
        KP[c0 + ch * 4 + 1][r] = kq.y;
        KP[c0 + ch * 4 + 2][r] = kq.z;
        KP[c0 + ch * 4 + 3][r] = kq.w;
        *(float4*)(&Vs[r][c0 + ch * 4]) = *(const float4*)(Vrow + ch * 4);
      }
    }
    __syncthreads();
    float S[4][4] = {};
    for (int kk = 0; kk < 64; ++kk) {
      float4 qv = *(const float4*)(&Qst[kk][ty << 2]);
      float4 kv = *(const float4*)(&KP[kk][tx << 2]);
      float qa[4] = {qv.x, qv.y, qv.z, qv.w};
      float ka[4] = {kv.x, kv.y, kv.z, kv.w};
#pragma unroll
      for (int i = 0; i < 4; ++i)
#pragma unroll
        for (int j2 = 0; j2 < 4; ++j2) S[i][j2] = fmaf(qa[i], ka[j2], S[i][j2]);
    }
    float p[4][4], scl[4];
#pragma unroll
    for (int i = 0; i < 4; ++i) {
      float mloc = fmaxf(fmaxf(S[i][0], S[i][1]), fmaxf(S[i][2], S[i][3]));
      for (int off = 1; off < 16; off <<= 1) mloc = fmaxf(mloc, __shfl_xor(mloc, off, 64));
      float mnew = fmaxf(m[i], mloc);
      scl[i] = expf(m[i] - mnew);
      float rs = 0.f;
#pragma unroll
      for (int j2 = 0; j2 < 4; ++j2) { p[i][j2] = expf(S[i][j2] - mnew); rs += p[i][j2]; }
      for (int off = 1; off < 16; off <<= 1) rs += __shfl_xor(rs, off, 64);
      l[i] = l[i] * scl[i] + rs;
      m[i] = mnew;
    }
    __syncthreads();
#pragma unroll
    for (int i = 0; i < 4; ++i) {
#pragma unroll
      for (int j2 = 0; j2 < 4; ++j2) {
        O[i][j2] *= scl[i];
        KP[(ty << 2) + i][(tx << 2) + j2] = p[i][j2];
      }
    }
    __syncthreads();
    for (int c = 0; c < 64; ++c) {
      float4 v4 = *(const float4*)(&Vs[c][tx << 2]);
      float va[4] = {v4.x, v4.y, v4.z, v4.w};
#pragma unroll
      for (int i = 0; i < 4; ++i) {
        float ps = KP[(ty << 2) + i][c];
#pragma unroll
        for (int j2 = 0; j2 < 4; ++j2) O[i][j2] = fmaf(ps, va[j2], O[i][j2]);
      }
    }
  }
  float* Ob = Out + ((size_t)bh * L + q0) * D;
#pragma unroll
  for (int i = 0; i < 4; ++i) {
    float inv = 1.f / l[i];
    float4 o4;
    o4.x = O[i][0] * inv; o4.y = O[i][1] * inv;
    o4.z = O[i][2] * inv; o4.w = O[i][3] * inv;
    *(float4*)(Ob + ((ty << 2) + i) * 64 + (tx << 2)) = o4;
  }
}

// ---------------- Kernel 6: finalize loss ----------------
__global__ void k_final(const double* __restrict__ dsc, float* __restrict__ out) {
  out[4194304] = (float)(-dsc[0] / 40960.0 - dsc[1] / 40.0);
}

extern "C" void kernel_launch(void* const* d_in, const int* in_sizes, int n_in,
                              void* d_out, int out_size, void* d_ws, size_t ws_size,
                              hipStream_t stream) {
  const float* Q   = (const float*)d_in[0];
  const float* K   = (const float*)d_in[1];
  const float* V   = (const float*)d_in[2];
  const float* wpk = (const float*)d_in[3];
  const float* bpk = (const float*)d_in[4];
  const float* wpb = (const float*)d_in[5];
  const float* bpb = (const float*)d_in[6];
  const float* wck = (const float*)d_in[7];
  const float* bck = (const float*)d_in[8];
  const float* wcq = (const float*)d_in[9];
  const float* bcq = (const float*)d_in[10];
  float* out = (float*)d_out;
  float* ws = (float*)d_ws;
  float* part = ws + WS_PART;
  float* mu   = ws + WS_MU;
  float* q2   = ws + WS_Q2;
  float* keff = ws + WS_KEFF;
  double* dsc = (double*)((char*)d_ws + WS_SCAL_BYTES);

  hipMemsetAsync((char*)d_ws + WS_SCAL_BYTES, 0, 16, stream);
  k_part<<<dim3(16, 5, 8), 64, 0, stream>>>(K, wpk, part);
  k_chain<<<32, 256, 0, stream>>>(part, bpk, wck, bck, wcq, bcq, mu, q2, dsc);
  k_ce<<<40, 256, 0, stream>>>(mu, dsc);
  k_keff<<<16384, 256, 0, stream>>>(q2, wpb, bpb, keff);
  k_attn<<<dim3(16, 64), 256, 0, stream>>>(Q, keff, V, out);
  k_final<<<1, 1, 0, stream>>>(dsc, out);
}

// Round 2
// 327.163 us; speedup vs baseline: 1.6810x; 1.6810x over previous
//
#include <hip/hip_runtime.h>
#include <math.h>

#define L 1024
#define D 64
#define H 8
#define B 8

// ws layout (float offsets)
#define WS_PART 0                 // 8*1024*5*15 = 614400
#define WS_MU   614400            // 8*1024*5    = 40960
#define WS_Q2   655360            // 8*1024*25   = 204800
#define WS_KEFF 860160            // 8*8*1024*64 = 4194304
#define WS_SCAL_BYTES 20217856    // 2 doubles (lp_sum, ce_sum)

typedef __attribute__((ext_vector_type(8))) short bf16x8;
typedef __attribute__((ext_vector_type(4))) float f32x4;

__device__ __forceinline__ ushort f2bf(float x) {
  unsigned b = __builtin_bit_cast(unsigned, x);
  return (ushort)((b + 0x7FFFu + ((b >> 16) & 1u)) >> 16);
}
__device__ __forceinline__ float bf2f(ushort u) {
  unsigned t = ((unsigned)u) << 16;
  return __builtin_bit_cast(float, t);
}

// ---------------- Kernel 1: conv1 partials ----------------
// part[bi][li][jj][nc*3+t] = sum_c K_unfold[bi,c,li,jj] * w_proj_k[nc,c,t]
__global__ __launch_bounds__(256) void k_part(const float* __restrict__ K,
                                              const float* __restrict__ wpk,
                                              float* __restrict__ part) {
  const int tid = threadIdx.x;
  const int lane = tid & 63;
  const int wid = tid >> 6;
  const int lq = blockIdx.x;   // 0..15  (li >> 6)
  const int jj = blockIdx.y;   // 0..4
  const int bi = blockIdx.z;   // 0..7
  __shared__ float w_s[512 * 16];
  __shared__ float red[3][64][16];
  for (int i = tid; i < 512 * 15; i += 256) {
    int c = i / 15, f = i % 15;
    int nc = f / 3, t = f % 3;
    w_s[c * 16 + f] = wpk[(nc * 512 + c) * 3 + t];
  }
  __syncthreads();
  float acc[15];
#pragma unroll
  for (int f = 0; f < 15; ++f) acc[f] = 0.f;
  if (bi + jj >= 5) {
    const float* Kb = K + (size_t)(bi + jj - 4) * (H * L * D);
    int c0 = wid * 128;
#pragma unroll 4
    for (int c = c0; c < c0 + 128; ++c) {
      int hh = c >> 6;
      int li2 = ((c & 63) << 4) + lq;
      float val = Kb[(hh * L + li2) * D + lane];
      const float* wr = &w_s[c * 16];
#pragma unroll
      for (int f = 0; f < 15; ++f) acc[f] = fmaf(val, wr[f], acc[f]);
    }
  }
  if (wid) {
#pragma unroll
    for (int f = 0; f < 15; ++f) red[wid - 1][lane][f] = acc[f];
  }
  __syncthreads();
  if (wid == 0) {
#pragma unroll
    for (int f = 0; f < 15; ++f)
      acc[f] += red[0][lane][f] + red[1][lane][f] + red[2][lane][f];
    int li = (lq << 6) + lane;
    float* dst = part + ((size_t)(bi * L + li) * 5 + jj) * 15;
#pragma unroll
    for (int f = 0; f < 15; ++f) dst[f] = acc[f];
  }
}

// ---------------- Kernel 2: per-(bi,li) chain ----------------
__global__ __launch_bounds__(256) void k_chain(const float* __restrict__ part,
    const float* __restrict__ b_pk, const float* __restrict__ w_ck,
    const float* __restrict__ b_ck, const float* __restrict__ w_cq,
    const float* __restrict__ b_cq, float* __restrict__ mu_out,
    float* __restrict__ q2_out, double* __restrict__ dsc) {
  int g = blockIdx.x * 256 + threadIdx.x;  // 0..8191 == bi*1024+li
  const float* p = part + (size_t)g * 75;
  float ckp[5][5];
#pragma unroll
  for (int j = 0; j < 5; ++j) {
#pragma unroll
    for (int nc = 0; nc < 5; ++nc) {
      float s = b_pk[nc];
#pragma unroll
      for (int t = 0; t < 3; ++t) {
        int w = j + t - 1;
        if (w >= 0 && w < 5) s += p[w * 15 + nc * 3 + t];
      }
      ckp[j][nc] = fmaxf(s, 0.f);
    }
  }
  float cq[5][5], ck[5][5];
  float lp_sum = 0.f;
#pragma unroll
  for (int j = 0; j < 5; ++j) {
    float vk[5], vq[5];
#pragma unroll
    for (int m = 0; m < 5; ++m) {
      float sk = b_ck[m], sq = b_cq[m];
#pragma unroll
      for (int n = 0; n < 5; ++n) {
        sk = fmaf(ckp[j][n], w_ck[m * 5 + n], sk);
        sq = fmaf(ckp[j][n], w_cq[m * 5 + n], sq);
      }
      vk[m] = sk; vq[m] = sq;
    }
    float mk = vk[0], mq = vq[0];
#pragma unroll
    for (int m = 1; m < 5; ++m) { mk = fmaxf(mk, vk[m]); mq = fmaxf(mq, vq[m]); }
    float sk = 0.f, sq = 0.f;
#pragma unroll
    for (int m = 0; m < 5; ++m) {
      vk[m] = expf(vk[m] - mk); sk += vk[m];
      vq[m] = expf(vq[m] - mq); sq += vq[m];
    }
    float rk = 1.f / sk, rq = 1.f / sq;
    float mu = 0.f, x = 0.f;
#pragma unroll
    for (int m = 0; m < 5; ++m) {
      ck[j][m] = vk[m] * rk; cq[j][m] = vq[m] * rq;
      mu += cq[j][m]; x += ck[j][m];
    }
    mu *= 0.2f; x *= 0.2f;
    float var = 0.f;
#pragma unroll
    for (int m = 0; m < 5; ++m) { float d0 = cq[j][m] - mu; var += d0 * d0; }
    var *= 0.25f;  // ddof=1
    float sg = log1pf(expf(sqrtf(var)));   // softplus(std)
    float z = (x - mu) / sg;
    lp_sum += -0.5f * z * z - logf(sg) - 0.91893853320467274f;
    mu_out[(size_t)g * 5 + j] = mu;
  }
  // masked triangular cluster attention -> q2
  float* q2p = q2_out + (size_t)g * 25;
#pragma unroll
  for (int pp = 0; pp < 5; ++pp) {
    float sc[5]; float mx = -3.0e38f;
    for (int u2 = 0; u2 <= pp; ++u2) {
      float d0 = 0.f;
#pragma unroll
      for (int c = 0; c < 5; ++c) d0 = fmaf(cq[pp][c], ck[u2][c], d0);
      sc[u2] = d0 * 0.2f;
      mx = fmaxf(mx, sc[u2]);
    }
    float den = 0.f;
    for (int u2 = 0; u2 <= pp; ++u2) { sc[u2] = expf(sc[u2] - mx); den += sc[u2]; }
    float rd = 1.f / den;
    float q2v[5] = {0.f, 0.f, 0.f, 0.f, 0.f};
    for (int u2 = 0; u2 <= pp; ++u2) {
      float a = sc[u2] * rd;
#pragma unroll
      for (int c = 0; c < 5; ++c) q2v[c] = fmaf(a, cq[u2][c], q2v[c]);
    }
#pragma unroll
    for (int c = 0; c < 5; ++c) q2p[pp * 5 + c] = q2v[c];
  }
  // reduce log_prob sum
  for (int off = 1; off < 64; off <<= 1) lp_sum += __shfl_xor(lp_sum, off, 64);
  __shared__ float wsum[4];
  int tid = threadIdx.x;
  if ((tid & 63) == 0) wsum[tid >> 6] = lp_sum;
  __syncthreads();
  if (tid == 0) atomicAdd(dsc, (double)(wsum[0] + wsum[1] + wsum[2] + wsum[3]));
}

// ---------------- Kernel 3: CE over l axis ----------------
__global__ __launch_bounds__(256) void k_ce(const float* __restrict__ mu,
                                            double* __restrict__ dsc) {
  int bi = blockIdx.x / 5, u = blockIdx.x % 5;
  int tid = threadIdx.x;
  const float* base = mu + (size_t)bi * L * 5 + u;
  float v[4];
#pragma unroll
  for (int k = 0; k < 4; ++k) v[k] = base[(tid + 256 * k) * 5];
  float mx = fmaxf(fmaxf(v[0], v[1]), fmaxf(v[2], v[3]));
  for (int off = 1; off < 64; off <<= 1) mx = fmaxf(mx, __shfl_xor(mx, off, 64));
  __shared__ float sh[4];
  if ((tid & 63) == 0) sh[tid >> 6] = mx;
  __syncthreads();
  mx = fmaxf(fmaxf(sh[0], sh[1]), fmaxf(sh[2], sh[3]));
  __syncthreads();
  float se = 0.f;
#pragma unroll
  for (int k = 0; k < 4; ++k) se += expf(v[k] - mx);
  for (int off = 1; off < 64; off <<= 1) se += __shfl_xor(se, off, 64);
  if ((tid & 63) == 0) sh[tid >> 6] = se;
  __syncthreads();
  float lse = mx + logf(sh[0] + sh[1] + sh[2] + sh[3]);
  __syncthreads();
  float part = 0.f;
#pragma unroll
  for (int k = 0; k < 4; ++k) part += v[k] * (v[k] - lse);
  for (int off = 1; off < 64; off <<= 1) part += __shfl_xor(part, off, 64);
  if ((tid & 63) == 0) sh[tid >> 6] = part;
  __syncthreads();
  if (tid == 0) atomicAdd(dsc + 1, (double)(sh[0] + sh[1] + sh[2] + sh[3]));
}

// ---------------- Kernel 4: back-projection + cluster sum -> Keff ----------------
__global__ __launch_bounds__(256) void k_keff(const float* __restrict__ q2,
    const float* __restrict__ wb, const float* __restrict__ bb,
    float* __restrict__ keff) {
  int g = blockIdx.x * 256 + threadIdx.x;  // over b*h*l*d
  int bi = g >> 19;
  int r = g & 524287;
  int hh = r >> 16;
  int li2 = (r >> 6) & 1023;
  int dd = r & 63;
  int base = hh * 327680 + li2 * 64 + dd;
  const float* q2b = q2 + (size_t)bi * L * 25;
  float sum = 0.f;
#pragma unroll
  for (int cc = 0; cc < 5; ++cc) {
    int flat = base + cc * 65536;
    int co = (int)((unsigned)flat / 5120u);
    int rem = flat - co * 5120;
    int li = (int)((unsigned)rem / 5u);
    int j = rem - li * 5;
    const float* qr = q2b + li * 25;
    const float* wr = wb + co * 15;
    float s = bb[co];
#pragma unroll
    for (int t = 0; t < 3; ++t) {
      int w = j + t - 1;
      if (w >= 0 && w < 5) {
#pragma unroll
        for (int c = 0; c < 5; ++c) s = fmaf(qr[w * 5 + c], wr[c * 3 + t], s);
      }
    }
    sum += fmaxf(s, 0.f);
  }
  keff[g] = sum;
}

// ---------------- Kernel 5: MFMA flash attention (bf16 hi/lo split) ----------------
// Block: 256 thr (4 waves), BQ=128 (32 q/wave), key tiles of 64.
// Swapped QK^T: S^T = mfma(K, Q) so P is lane-local for PV.
// Claimed k-bijection for all A/B frags: f(g,j) = 4g + (j&3) + 16*(j>>2) (+32*step).
__global__ __launch_bounds__(256) void k_attn(const float* __restrict__ Q,
    const float* __restrict__ Kf, const float* __restrict__ V,
    float* __restrict__ Out) {
  __shared__ ushort Khi[4096], Klo[4096];   // [key][d] bf16, chunk^= (key&15)
  __shared__ ushort Vthi[4096], Vtlo[4096]; // [d][key] bf16, chunk^= (d&15)
  const int tid = threadIdx.x;
  const int lane = tid & 63;
  const int w = tid >> 6;
  const int lq = lane & 15;
  const int g = lane >> 4;
  const int bh = blockIdx.y;
  const int q0 = blockIdx.x << 7;   // BQ=128
  const float* Qb = Q + ((size_t)bh * L + q0 + w * 32) * D;
  const float* Kb = Kf + (size_t)bh * L * D;
  const float* Vb = V + (size_t)bh * L * D;

  // --- Q fragments, hoisted (hi/lo) : [qsub][ds] ---
  bf16x8 qh[2][2], qlo[2][2];
#pragma unroll
  for (int qs = 0; qs < 2; ++qs) {
    const float* Qr = Qb + (qs * 16 + lq) * D;
#pragma unroll
    for (int ds = 0; ds < 2; ++ds) {
      float4 x0 = *(const float4*)(Qr + 4 * g + 32 * ds);
      float4 x1 = *(const float4*)(Qr + 4 * g + 16 + 32 * ds);
      float xs[8] = {x0.x, x0.y, x0.z, x0.w, x1.x, x1.y, x1.z, x1.w};
      bf16x8 h, l;
#pragma unroll
      for (int j = 0; j < 8; ++j) {
        ushort hb = f2bf(xs[j]);
        h[j] = (short)hb;
        l[j] = (short)f2bf(xs[j] - bf2f(hb));
      }
      qh[qs][ds] = h; qlo[qs][ds] = l;
    }
  }

  f32x4 O_[2][4];
  float m_[2], l_[2];
#pragma unroll
  for (int qs = 0; qs < 2; ++qs) {
    m_[qs] = -3.0e38f; l_[qs] = 0.f;
#pragma unroll
    for (int d2 = 0; d2 < 4; ++d2) O_[qs][d2] = (f32x4){0.f, 0.f, 0.f, 0.f};
  }

  for (int kt = 0; kt < 16; ++kt) {
    __syncthreads();
    // --- stage K tile: [key][d] swizzled ---
    {
      int key = tid >> 2, c0 = (tid & 3) << 4;
      const float* Krow = Kb + (kt * 64 + key) * 64 + c0;
#pragma unroll
      for (int i = 0; i < 4; ++i) {
        float4 v = *(const float4*)(Krow + 4 * i);
        ushort4 h, lo;
        h.x = f2bf(v.x); h.y = f2bf(v.y); h.z = f2bf(v.z); h.w = f2bf(v.w);
        lo.x = f2bf(v.x - bf2f(h.x)); lo.y = f2bf(v.y - bf2f(h.y));
        lo.z = f2bf(v.z - bf2f(h.z)); lo.w = f2bf(v.w - bf2f(h.w));
        int c = (c0 >> 2) + i;
        int idx = key * 64 + ((c ^ (key & 15)) << 2);
        *(ushort4*)(&Khi[idx]) = h;
        *(ushort4*)(&Klo[idx]) = lo;
      }
    }
    // --- stage V tile transposed: Vt[d][key] swizzled ---
    {
      int kp = tid & 31, dblk = tid >> 5;  // 2 keys x 8 d's per thread
      ushort vh[2][8], vl[2][8];
#pragma unroll
      for (int kk = 0; kk < 2; ++kk) {
        int key = 2 * kp + kk;
        const float* Vrow = Vb + (kt * 64 + key) * 64 + dblk * 8;
#pragma unroll
        for (int i = 0; i < 2; ++i) {
          float4 v = *(const float4*)(Vrow + 4 * i);
          float xs[4] = {v.x, v.y, v.z, v.w};
#pragma unroll
          for (int e = 0; e < 4; ++e) {
            ushort hb = f2bf(xs[e]);
            vh[kk][4 * i + e] = hb;
            vl[kk][4 * i + e] = f2bf(xs[e] - bf2f(hb));
          }
        }
      }
#pragma unroll
      for (int dd = 0; dd < 8; ++dd) {
        int d = dblk * 8 + dd;
        int idx = d * 64 + (((kp >> 1) ^ (d & 15)) << 2) + ((kp & 1) << 1);
        ushort2 ph; ph.x = vh[0][dd]; ph.y = vh[1][dd];
        ushort2 pl; pl.x = vl[0][dd]; pl.y = vl[1][dd];
        *(ushort2*)(&Vthi[idx]) = ph;
        *(ushort2*)(&Vtlo[idx]) = pl;
      }
    }
    __syncthreads();

    // --- S^T = K * Q^T  (rows=keys, cols=q) ---
    f32x4 S[4][2];
#pragma unroll
    for (int ks = 0; ks < 4; ++ks)
#pragma unroll
      for (int qs = 0; qs < 2; ++qs) S[ks][qs] = (f32x4){0.f, 0.f, 0.f, 0.f};
#pragma unroll
    for (int ds = 0; ds < 2; ++ds) {
#pragma unroll
      for (int ksub = 0; ksub < 4; ++ksub) {
        int key = ksub * 16 + lq;
        int base = key * 64;
        int ca = ((g + 8 * ds) ^ lq) << 2;
        int cb = ((g + 4 + 8 * ds) ^ lq) << 2;
        ushort4 a0 = *(const ushort4*)(&Khi[base + ca]);
        ushort4 a1 = *(const ushort4*)(&Khi[base + cb]);
        ushort4 b0 = *(const ushort4*)(&Klo[base + ca]);
        ushort4 b1 = *(const ushort4*)(&Klo[base + cb]);
        bf16x8 kh = {(short)a0.x, (short)a0.y, (short)a0.z, (short)a0.w,
                     (short)a1.x, (short)a1.y, (short)a1.z, (short)a1.w};
        bf16x8 kl = {(short)b0.x, (short)b0.y, (short)b0.z, (short)b0.w,
                     (short)b1.x, (short)b1.y, (short)b1.z, (short)b1.w};
#pragma unroll
        for (int qs = 0; qs < 2; ++qs) {
          S[ksub][qs] = __builtin_amdgcn_mfma_f32_16x16x32_bf16(kh, qh[qs][ds], S[ksub][qs], 0, 0, 0);
          S[ksub][qs] = __builtin_amdgcn_mfma_f32_16x16x32_bf16(kh, qlo[qs][ds], S[ksub][qs], 0, 0, 0);
          S[ksub][qs] = __builtin_amdgcn_mfma_f32_16x16x32_bf16(kl, qh[qs][ds], S[ksub][qs], 0, 0, 0);
        }
      }
    }

    // --- online softmax (per qsub; query = lq, keys = 16*ksub + 4g + reg) ---
    bf16x8 pfh[2][2], pfl[2][2];  // [qsub][kstep]
#pragma unroll
    for (int qs = 0; qs < 2; ++qs) {
      float tmax = -3.0e38f;
#pragma unroll
      for (int ks = 0; ks < 4; ++ks)
#pragma unroll
        for (int r = 0; r < 4; ++r) tmax = fmaxf(tmax, S[ks][qs][r]);
      tmax = fmaxf(tmax, __shfl_xor(tmax, 16, 64));
      tmax = fmaxf(tmax, __shfl_xor(tmax, 32, 64));
      float mn = fmaxf(m_[qs], tmax);
      float scl = __expf(m_[qs] - mn);
      float p[4][4]; float rs = 0.f;
#pragma unroll
      for (int ks = 0; ks < 4; ++ks)
#pragma unroll
        for (int r = 0; r < 4; ++r) {
          float pv = __expf(S[ks][qs][r] - mn);
          p[ks][r] = pv; rs += pv;
        }
      rs += __shfl_xor(rs, 16, 64);
      rs += __shfl_xor(rs, 32, 64);
      l_[qs] = l_[qs] * scl + rs;
      m_[qs] = mn;
      // pack P fragments (keys f(g,j)+32*kstep with ksub = (j>>2) + 2*kstep)
#pragma unroll
      for (int kst = 0; kst < 2; ++kst) {
        bf16x8 h, l;
#pragma unroll
        for (int jh = 0; jh < 2; ++jh)
#pragma unroll
          for (int j2 = 0; j2 < 4; ++j2) {
            float pv = p[jh + 2 * kst][j2];
            ushort hb = f2bf(pv);
            h[jh * 4 + j2] = (short)hb;
            l[jh * 4 + j2] = (short)f2bf(pv - bf2f(hb));
          }
        pfh[qs][kst] = h; pfl[qs][kst] = l;
      }
      // rescale O (O rows = 4g + reg within qsub)
      float sr[4];
#pragma unroll
      for (int r = 0; r < 4; ++r) sr[r] = __shfl(scl, 4 * g + r, 64);
#pragma unroll
      for (int d2 = 0; d2 < 4; ++d2)
#pragma unroll
        for (int r = 0; r < 4; ++r) O_[qs][d2][r] *= sr[r];
    }

    // --- PV: O += P * V ---
#pragma unroll
    for (int kst = 0; kst < 2; ++kst) {
#pragma unroll
      for (int d2 = 0; d2 < 4; ++d2) {
        int d = d2 * 16 + lq;
        int base = d * 64;
        int ca = ((g + 8 * kst) ^ lq) << 2;
        int cb = ((g + 4 + 8 * kst) ^ lq) << 2;
        ushort4 a0 = *(const ushort4*)(&Vthi[base + ca]);
        ushort4 a1 = *(const ushort4*)(&Vthi[base + cb]);
        ushort4 b0 = *(const ushort4*)(&Vtlo[base + ca]);
        ushort4 b1 = *(const ushort4*)(&Vtlo[base + cb]);
        bf16x8 vh = {(short)a0.x, (short)a0.y, (short)a0.z, (short)a0.w,
                     (short)a1.x, (short)a1.y, (short)a1.z, (short)a1.w};
        bf16x8 vl = {(short)b0.x, (short)b0.y, (short)b0.z, (short)b0.w,
                     (short)b1.x, (short)b1.y, (short)b1.z, (short)b1.w};
#pragma unroll
        for (int qs = 0; qs < 2; ++qs) {
          O_[qs][d2] = __builtin_amdgcn_mfma_f32_16x16x32_bf16(pfh[qs][kst], vh, O_[qs][d2], 0, 0, 0);
          O_[qs][d2] = __builtin_amdgcn_mfma_f32_16x16x32_bf16(pfl[qs][kst], vh, O_[qs][d2], 0, 0, 0);
          O_[qs][d2] = __builtin_amdgcn_mfma_f32_16x16x32_bf16(pfh[qs][kst], vl, O_[qs][d2], 0, 0, 0);
        }
      }
    }
  }

  // --- epilogue: divide by l, store (O row = q = 16*qsub + 4g + reg, col d = 16*d2 + lq) ---
  float* Ob = Out + ((size_t)bh * L + q0 + w * 32) * D;
#pragma unroll
  for (int qs = 0; qs < 2; ++qs) {
    float il = 1.f / l_[qs];
    float ir[4];
#pragma unroll
    for (int r = 0; r < 4; ++r) ir[r] = __shfl(il, 4 * g + r, 64);
#pragma unroll
    for (int d2 = 0; d2 < 4; ++d2) {
#pragma unroll
      for (int r = 0; r < 4; ++r) {
        int row = qs * 16 + 4 * g + r;
        Ob[row * D + d2 * 16 + lq] = O_[qs][d2][r] * ir[r];
      }
    }
  }
}

// ---------------- Kernel 6: finalize loss ----------------
__global__ void k_final(const double* __restrict__ dsc, float* __restrict__ out) {
  out[4194304] = (float)(-dsc[0] / 40960.0 - dsc[1] / 40.0);
}

extern "C" void kernel_launch(void* const* d_in, const int* in_sizes, int n_in,
                              void* d_out, int out_size, void* d_ws, size_t ws_size,
                              hipStream_t stream) {
  const float* Q   = (const float*)d_in[0];
  const float* K   = (const float*)d_in[1];
  const float* V   = (const float*)d_in[2];
  const float* wpk = (const float*)d_in[3];
  const float* bpk = (const float*)d_in[4];
  const float* wpb = (const float*)d_in[5];
  const float* bpb = (const float*)d_in[6];
  const float* wck = (const float*)d_in[7];
  const float* bck = (const float*)d_in[8];
  const float* wcq = (const float*)d_in[9];
  const float* bcq = (const float*)d_in[10];
  float* out = (float*)d_out;
  float* ws = (float*)d_ws;
  float* part = ws + WS_PART;
  float* mu   = ws + WS_MU;
  float* q2   = ws + WS_Q2;
  float* keff = ws + WS_KEFF;
  double* dsc = (double*)((char*)d_ws + WS_SCAL_BYTES);

  hipMemsetAsync((char*)d_ws + WS_SCAL_BYTES, 0, 16, stream);
  k_part<<<dim3(16, 5, 8), 256, 0, stream>>>(K, wpk, part);
  k_chain<<<32, 256, 0, stream>>>(part, bpk, wck, bck, wcq, bcq, mu, q2, dsc);
  k_ce<<<40, 256, 0, stream>>>(mu, dsc);
  k_keff<<<16384, 256, 0, stream>>>(q2, wpb, bpb, keff);
  k_attn<<<dim3(8, 64), 256, 0, stream>>>(Q, keff, V, out);
  k_final<<<1, 1, 0, stream>>>(dsc, out);
}

// Round 5
// 307.893 us; speedup vs baseline: 1.7863x; 1.0626x over previous
//
#include <hip/hip_runtime.h>
#include <math.h>

#define L 1024
#define D 64
#define H 8
#define B 8

// ---------------- ws layout ----------------
// floats:
#define WS_G    0            // 7*1024*15 = 107520   (G[bi'-1][li][15], bi'=1..7)
#define WS_MU   107520       // 8*1024*5  = 40960
#define WS_Q2   148480       // 8*1024*25 = 204800   (ends 353280)
// bytes:
#define WS_DSC_BYTE   1413120u   // 2 doubles
#define WS_KHI_BYTE   1413632u   // 8,388,608 B (64bh*16kt*4096 ushort)
#define WS_KLO_BYTE   9802240u
#define WS_NOV_END    18190848u  // known-safe (ws >= 20.2MB proven in R1/R2)
#define WS_VTHI_BYTE  18190848u
#define WS_VTLO_BYTE  26579456u
#define WS_V_END      34968064u

typedef __attribute__((ext_vector_type(8))) short bf16x8;
typedef __attribute__((ext_vector_type(4))) float f32x4;

__device__ __forceinline__ ushort f2bf(float x) {
  unsigned b = __builtin_bit_cast(unsigned, x);
  return (ushort)((b + 0x7FFFu + ((b >> 16) & 1u)) >> 16);
}
__device__ __forceinline__ float bf2f(ushort u) {
  unsigned t = ((unsigned)u) << 16;
  return __builtin_bit_cast(float, t);
}

// ---------------- Kernel 1: conv1 partials (jj-collapsed) ----------------
// G[bi'-1][li][f] = sum_c K_unfold-col(bi',li,c) * w[c][f]; part[bi][li][jj] == G[bi+jj-4]
__global__ __launch_bounds__(256) void k_part(const float* __restrict__ K,
                                              const float* __restrict__ wpk,
                                              float* __restrict__ G) {
  const int tid = threadIdx.x, lane = tid & 63, wid = tid >> 6;
  const int lq = blockIdx.x;        // 0..15
  const int bip = blockIdx.y + 1;   // 1..7
  __shared__ float w_s[512 * 16];
  __shared__ float red[3][64][16];
  for (int i = tid; i < 512 * 16; i += 256) {
    int c = i >> 4, f = i & 15;
    w_s[i] = (f < 15) ? wpk[((f / 3) * 512 + c) * 3 + (f % 3)] : 0.f;
  }
  __syncthreads();
  float acc[15];
#pragma unroll
  for (int f = 0; f < 15; ++f) acc[f] = 0.f;
  const float* Kb = K + (size_t)bip * (H * L * D);
  const int c0 = wid * 128;
#pragma unroll 4
  for (int c = c0; c < c0 + 128; ++c) {
    float val = Kb[((c >> 6) * L + ((c & 63) << 4) + lq) * D + lane];
    const float4* wr = (const float4*)&w_s[c * 16];
    float4 w0 = wr[0], w1 = wr[1], w2 = wr[2], w3 = wr[3];
    acc[0] = fmaf(val, w0.x, acc[0]);  acc[1] = fmaf(val, w0.y, acc[1]);
    acc[2] = fmaf(val, w0.z, acc[2]);  acc[3] = fmaf(val, w0.w, acc[3]);
    acc[4] = fmaf(val, w1.x, acc[4]);  acc[5] = fmaf(val, w1.y, acc[5]);
    acc[6] = fmaf(val, w1.z, acc[6]);  acc[7] = fmaf(val, w1.w, acc[7]);
    acc[8] = fmaf(val, w2.x, acc[8]);  acc[9] = fmaf(val, w2.y, acc[9]);
    acc[10] = fmaf(val, w2.z, acc[10]); acc[11] = fmaf(val, w2.w, acc[11]);
    acc[12] = fmaf(val, w3.x, acc[12]); acc[13] = fmaf(val, w3.y, acc[13]);
    acc[14] = fmaf(val, w3.z, acc[14]);
  }
  if (wid) {
#pragma unroll
    for (int f = 0; f < 15; ++f) red[wid - 1][lane][f] = acc[f];
  }
  __syncthreads();
  if (wid == 0) {
#pragma unroll
    for (int f = 0; f < 15; ++f)
      acc[f] += red[0][lane][f] + red[1][lane][f] + red[2][lane][f];
    float* dst = G + ((size_t)blockIdx.y * 1024 + (lq << 6) + lane) * 15;
#pragma unroll
    for (int f = 0; f < 15; ++f) dst[f] = acc[f];
  }
}

// ---------------- Kernel 2: per-(bi,li) chain ----------------
__global__ __launch_bounds__(256) void k_chain(const float* __restrict__ G,
    const float* __restrict__ b_pk, const float* __restrict__ w_ck,
    const float* __restrict__ b_ck, const float* __restrict__ w_cq,
    const float* __restrict__ b_cq, float* __restrict__ mu_out,
    float* __restrict__ q2_out, double* __restrict__ dsc) {
  int g = blockIdx.x * 256 + threadIdx.x;  // bi*1024+li
  int bi = g >> 10, li = g & 1023;
  float ckp[5][5];
#pragma unroll
  for (int j = 0; j < 5; ++j) {
#pragma unroll
    for (int nc = 0; nc < 5; ++nc) {
      float s = b_pk[nc];
#pragma unroll
      for (int t = 0; t < 3; ++t) {
        int w = j + t - 1;
        int bip = bi + w - 4;
        if (w >= 0 && w < 5 && bip >= 1)
          s += G[(size_t)((bip - 1) * 1024 + li) * 15 + nc * 3 + t];
      }
      ckp[j][nc] = fmaxf(s, 0.f);
    }
  }
  float cq[5][5], ck[5][5];
  float lp_sum = 0.f;
#pragma unroll
  for (int j = 0; j < 5; ++j) {
    float vk[5], vq[5];
#pragma unroll
    for (int m = 0; m < 5; ++m) {
      float sk = b_ck[m], sq = b_cq[m];
#pragma unroll
      for (int n = 0; n < 5; ++n) {
        sk = fmaf(ckp[j][n], w_ck[m * 5 + n], sk);
        sq = fmaf(ckp[j][n], w_cq[m * 5 + n], sq);
      }
      vk[m] = sk; vq[m] = sq;
    }
    float mk = vk[0], mq = vq[0];
#pragma unroll
    for (int m = 1; m < 5; ++m) { mk = fmaxf(mk, vk[m]); mq = fmaxf(mq, vq[m]); }
    float sk = 0.f, sq = 0.f;
#pragma unroll
    for (int m = 0; m < 5; ++m) {
      vk[m] = expf(vk[m] - mk); sk += vk[m];
      vq[m] = expf(vq[m] - mq); sq += vq[m];
    }
    float rk = 1.f / sk, rq = 1.f / sq;
    float mu = 0.f, x = 0.f;
#pragma unroll
    for (int m = 0; m < 5; ++m) {
      ck[j][m] = vk[m] * rk; cq[j][m] = vq[m] * rq;
      mu += cq[j][m]; x += ck[j][m];
    }
    mu *= 0.2f; x *= 0.2f;
    float var = 0.f;
#pragma unroll
    for (int m = 0; m < 5; ++m) { float d0 = cq[j][m] - mu; var += d0 * d0; }
    var *= 0.25f;
    float sg = log1pf(expf(sqrtf(var)));
    float z = (x - mu) / sg;
    lp_sum += -0.5f * z * z - logf(sg) - 0.91893853320467274f;
    mu_out[(size_t)g * 5 + j] = mu;
  }
  float* q2p = q2_out + (size_t)g * 25;
#pragma unroll
  for (int pp = 0; pp < 5; ++pp) {
    float sc[5]; float mx = -3.0e38f;
    for (int u2 = 0; u2 <= pp; ++u2) {
      float d0 = 0.f;
#pragma unroll
      for (int c = 0; c < 5; ++c) d0 = fmaf(cq[pp][c], ck[u2][c], d0);
      sc[u2] = d0 * 0.2f;
      mx = fmaxf(mx, sc[u2]);
    }
    float den = 0.f;
    for (int u2 = 0; u2 <= pp; ++u2) { sc[u2] = expf(sc[u2] - mx); den += sc[u2]; }
    float rd = 1.f / den;
    float q2v[5] = {0.f, 0.f, 0.f, 0.f, 0.f};
    for (int u2 = 0; u2 <= pp; ++u2) {
      float a = sc[u2] * rd;
#pragma unroll
      for (int c = 0; c < 5; ++c) q2v[c] = fmaf(a, cq[u2][c], q2v[c]);
    }
#pragma unroll
    for (int c = 0; c < 5; ++c) q2p[pp * 5 + c] = q2v[c];
  }
  for (int off = 1; off < 64; off <<= 1) lp_sum += __shfl_xor(lp_sum, off, 64);
  __shared__ float wsum[4];
  int tid = threadIdx.x;
  if ((tid & 63) == 0) wsum[tid >> 6] = lp_sum;
  __syncthreads();
  if (tid == 0) atomicAdd(dsc, (double)(wsum[0] + wsum[1] + wsum[2] + wsum[3]));
}

// ---------------- Kernel 3: CE over l axis ----------------
__global__ __launch_bounds__(256) void k_ce(const float* __restrict__ mu,
                                            double* __restrict__ dsc) {
  int bi = blockIdx.x / 5, u = blockIdx.x % 5;
  int tid = threadIdx.x;
  const float* base = mu + (size_t)bi * L * 5 + u;
  float v[4];
#pragma unroll
  for (int k = 0; k < 4; ++k) v[k] = base[(tid + 256 * k) * 5];
  float mx = fmaxf(fmaxf(v[0], v[1]), fmaxf(v[2], v[3]));
  for (int off = 1; off < 64; off <<= 1) mx = fmaxf(mx, __shfl_xor(mx, off, 64));
  __shared__ float sh[4];
  if ((tid & 63) == 0) sh[tid >> 6] = mx;
  __syncthreads();
  mx = fmaxf(fmaxf(sh[0], sh[1]), fmaxf(sh[2], sh[3]));
  __syncthreads();
  float se = 0.f;
#pragma unroll
  for (int k = 0; k < 4; ++k) se += expf(v[k] - mx);
  for (int off = 1; off < 64; off <<= 1) se += __shfl_xor(se, off, 64);
  if ((tid & 63) == 0) sh[tid >> 6] = se;
  __syncthreads();
  float lse = mx + logf(sh[0] + sh[1] + sh[2] + sh[3]);
  __syncthreads();
  float part = 0.f;
#pragma unroll
  for (int k = 0; k < 4; ++k) part += v[k] * (v[k] - lse);
  for (int off = 1; off < 64; off <<= 1) part += __shfl_xor(part, off, 64);
  if ((tid & 63) == 0) sh[tid >> 6] = part;
  __syncthreads();
  if (tid == 0) atomicAdd(dsc + 1, (double)(sh[0] + sh[1] + sh[2] + sh[3]));
}

// ---------------- Kernel 4: back-proj + cluster sum -> K-prep (bf16 hi/lo tile image) ----------------
__global__ __launch_bounds__(256) void k_kprep(const float* __restrict__ q2,
    const float* __restrict__ wb, const float* __restrict__ bb,
    ushort* __restrict__ Khi_g, ushort* __restrict__ Klo_g) {
  int g = blockIdx.x * 256 + threadIdx.x;  // [bi][hh][li][dd]
  int bi = g >> 19;
  int r = g & 524287;
  int hh = r >> 16;
  int li = (r >> 6) & 1023;
  int dd = r & 63;
  int base = hh * 327680 + li * 64 + dd;
  const float* q2b = q2 + (size_t)bi * L * 25;
  float sum = 0.f;
#pragma unroll
  for (int cc = 0; cc < 5; ++cc) {
    int flat = base + cc * 65536;
    int co = (int)((unsigned)flat / 5120u);
    int rem = flat - co * 5120;
    int li2 = (int)((unsigned)rem / 5u);
    int j = rem - li2 * 5;
    const float* qr = q2b + li2 * 25;
    const float* wr = wb + co * 15;
    float s = bb[co];
#pragma unroll
    for (int t = 0; t < 3; ++t) {
      int w = j + t - 1;
      if (w >= 0 && w < 5) {
#pragma unroll
        for (int c = 0; c < 5; ++c) s = fmaf(qr[w * 5 + c], wr[c * 3 + t], s);
      }
    }
    sum += fmaxf(s, 0.f);
  }
  // write bf16 hi/lo at swizzled tile-image position
  int kt = li >> 6, key = li & 63, c = dd >> 2, e = dd & 3;
  int idx = (((bi * 8 + hh) * 16 + kt) << 12) + (key << 6) + ((c ^ (key & 15)) << 2) + e;
  ushort hb = f2bf(sum);
  Khi_g[idx] = hb;
  Klo_g[idx] = f2bf(sum - bf2f(hb));
}

// ---------------- Kernel 4b: V -> transposed bf16 hi/lo tile image ----------------
__global__ __launch_bounds__(256) void k_vprep(const float* __restrict__ V,
    ushort* __restrict__ Vthi_g, ushort* __restrict__ Vtlo_g) {
  __shared__ float t[64][65];
  const int tile = blockIdx.x;  // bh*16+kt
  const float* Vb = V + ((size_t)tile << 12);
  const int tid = threadIdx.x;
  {
    int key = tid >> 2, c0 = (tid & 3) << 4;
#pragma unroll
    for (int i = 0; i < 4; ++i) {
      float4 v = *(const float4*)(Vb + key * 64 + c0 + 4 * i);
      t[key][c0 + 4 * i + 0] = v.x; t[key][c0 + 4 * i + 1] = v.y;
      t[key][c0 + 4 * i + 2] = v.z; t[key][c0 + 4 * i + 3] = v.w;
    }
  }
  __syncthreads();
  int d = tid >> 2, q4 = tid & 3;
#pragma unroll
  for (int q = 0; q < 4; ++q) {
    int kc = q4 * 4 + q;
    ushort hv[4], lv[4];
#pragma unroll
    for (int e = 0; e < 4; ++e) {
      float x = t[kc * 4 + e][d];
      ushort hb = f2bf(x);
      hv[e] = hb;
      lv[e] = f2bf(x - bf2f(hb));
    }
    int idx = (tile << 12) + (d << 6) + ((kc ^ (d & 15)) << 2);
    ushort4 h4; h4.x = hv[0]; h4.y = hv[1]; h4.z = hv[2]; h4.w = hv[3];
    ushort4 l4; l4.x = lv[0]; l4.y = lv[1]; l4.z = lv[2]; l4.w = lv[3];
    *(ushort4*)(&Vthi_g[idx]) = h4;
    *(ushort4*)(&Vtlo_g[idx]) = l4;
  }
}

// ---------------- Kernel 5: MFMA flash attention ----------------
// 4 waves, BQ=128. Double-buffered LDS staged by global_load_lds from prep images.
// QK^T swapped (S^T = K*Q); PV swapped back (O^T = V^T*P^T) so softmax stats
// and rescale are lane-local (zero shuffles outside the row-reduce).
template<bool VPREP>
__global__ __launch_bounds__(256) void k_attn(const float* __restrict__ Q,
    const ushort* __restrict__ Khi_g, const ushort* __restrict__ Klo_g,
    const ushort* __restrict__ Vthi_g, const ushort* __restrict__ Vtlo_g,
    const float* __restrict__ V, float* __restrict__ Out) {
  __shared__ ushort smem[2][16384];  // [buf][Khi 4K | Klo 4K | Vthi 4K | Vtlo 4K]
  const int tid = threadIdx.x;
  const int lane = tid & 63;
  const int w = tid >> 6;
  const int lq = lane & 15;
  const int g = lane >> 4;
  // XCD-aware decode: XCD x owns bh in [8x, 8x+8) (dispatch round-robin heuristic)
  const int id = blockIdx.x;                 // 0..511
  const int bh = ((id & 7) << 3) + (id >> 6);
  const int qb = (id >> 3) & 7;
  const int q0 = qb << 7;
  const float* Qb = Q + ((size_t)bh * L + q0 + w * 32) * D;
  const float* Vb = V + (size_t)bh * L * D;
  const int tb = bh * 16;

  // per-lane fragment chunk XORs (constant): chunks {g, g+4, g+8, g+12} ^ lq
  int cx0 = ((g) ^ lq) << 2, cx1 = ((g + 4) ^ lq) << 2;
  int cx2 = ((g + 8) ^ lq) << 2, cx3 = ((g + 12) ^ lq) << 2;

  // --- Q fragments (hi/lo), hoisted ---
  bf16x8 qh[2][2], qlo[2][2];
#pragma unroll
  for (int qs = 0; qs < 2; ++qs) {
    const float* Qr = Qb + (qs * 16 + lq) * D;
#pragma unroll
    for (int ds = 0; ds < 2; ++ds) {
      float4 x0 = *(const float4*)(Qr + 4 * g + 32 * ds);
      float4 x1 = *(const float4*)(Qr + 4 * g + 16 + 32 * ds);
      float xs[8] = {x0.x, x0.y, x0.z, x0.w, x1.x, x1.y, x1.z, x1.w};
      bf16x8 h, l;
#pragma unroll
      for (int j = 0; j < 8; ++j) {
        ushort hb = f2bf(xs[j]);
        h[j] = (short)hb;
        l[j] = (short)f2bf(xs[j] - bf2f(hb));
      }
      qh[qs][ds] = h; qlo[qs][ds] = l;
    }
  }

  // staging source base for this wave
  const ushort* warr;
  int wdst;
  if (VPREP) {
    warr = (w == 0) ? Khi_g : (w == 1) ? Klo_g : (w == 2) ? Vthi_g : Vtlo_g;
    wdst = w << 12;
  } else {
    warr = ((w < 2) ? Khi_g : Klo_g);
    wdst = ((w >> 1) << 12) + ((w & 1) << 11);
  }

#define STAGE(buf_, kt_) do {                                                  \
    const ushort* src_ = warr + ((size_t)(tb + (kt_)) << 12) +                 \
                         (VPREP ? 0 : ((w & 1) << 11)) + lane * 8;             \
    ushort* dst_ = &smem[buf_][wdst];                                          \
    _Pragma("unroll")                                                          \
    for (int r_ = 0; r_ < (VPREP ? 8 : 4); ++r_) {                             \
      __builtin_amdgcn_global_load_lds(                                        \
        (const __attribute__((address_space(1))) unsigned int*)(src_ + r_ * 512), \
        (__attribute__((address_space(3))) unsigned int*)(dst_ + r_ * 512 + lane * 8), \
        16, 0, 0);                                                             \
    }                                                                          \
  } while (0)

  float4 vreg[2][2];
  const int kp = tid & 31, dblk = tid >> 5;
#define VLOAD(kt_) do {                                                        \
    const float* Vb2_ = Vb + ((size_t)(kt_) << 12);                            \
    _Pragma("unroll")                                                          \
    for (int kk_ = 0; kk_ < 2; ++kk_)                                          \
      _Pragma("unroll")                                                        \
      for (int i_ = 0; i_ < 2; ++i_)                                           \
        vreg[kk_][i_] = *(const float4*)(Vb2_ + (2 * kp + kk_) * 64 + dblk * 8 + 4 * i_); \
  } while (0)
#define VWRITE(nb_) do {                                                       \
    ushort vh_[2][8], vl_[2][8];                                               \
    _Pragma("unroll")                                                          \
    for (int kk_ = 0; kk_ < 2; ++kk_)                                          \
      _Pragma("unroll")                                                        \
      for (int i_ = 0; i_ < 2; ++i_) {                                         \
        float xs_[4] = {vreg[kk_][i_].x, vreg[kk_][i_].y, vreg[kk_][i_].z, vreg[kk_][i_].w}; \
        _Pragma("unroll")                                                      \
        for (int e_ = 0; e_ < 4; ++e_) {                                       \
          ushort hb_ = f2bf(xs_[e_]);                                          \
          vh_[kk_][4 * i_ + e_] = hb_;                                         \
          vl_[kk_][4 * i_ + e_] = f2bf(xs_[e_] - bf2f(hb_));                   \
        }                                                                      \
      }                                                                        \
    _Pragma("unroll")                                                          \
    for (int dd_ = 0; dd_ < 8; ++dd_) {                                        \
      int d_ = dblk * 8 + dd_;                                                 \
      int idx_ = (d_ << 6) + (((kp >> 1) ^ (d_ & 15)) << 2) + ((kp & 1) << 1); \
      ushort2 ph_; ph_.x = vh_[0][dd_]; ph_.y = vh_[1][dd_];                   \
      ushort2 pl_; pl_.x = vl_[0][dd_]; pl_.y = vl_[1][dd_];                   \
      *(ushort2*)(&smem[nb_][8192 + idx_]) = ph_;                              \
      *(ushort2*)(&smem[nb_][12288 + idx_]) = pl_;                             \
    }                                                                          \
  } while (0)

  f32x4 O_[2][4];
  float m_[2], l_[2];
#pragma unroll
  for (int qs = 0; qs < 2; ++qs) {
    m_[qs] = -3.0e38f; l_[qs] = 0.f;
#pragma unroll
    for (int d2 = 0; d2 < 4; ++d2) O_[qs][d2] = (f32x4){0.f, 0.f, 0.f, 0.f};
  }

  // prologue: stage tile 0 into buf 0
  STAGE(0, 0);
  if (!VPREP) { VLOAD(0); VWRITE(0); }
  __syncthreads();

  int cur = 0;
  for (int kt = 0; kt < 16; ++kt) {
    // issue next tile's loads (overlap with compute)
    if (kt < 15) {
      STAGE(cur ^ 1, kt + 1);
      if (!VPREP) VLOAD(kt + 1);
    }

    const ushort* Kh = &smem[cur][0];
    const ushort* Kl = &smem[cur][4096];
    const ushort* Vh = &smem[cur][8192];
    const ushort* Vl = &smem[cur][12288];

    // --- S^T = K * Q^T ---
    f32x4 S[4][2];
#pragma unroll
    for (int ks = 0; ks < 4; ++ks)
#pragma unroll
      for (int qs = 0; qs < 2; ++qs) S[ks][qs] = (f32x4){0.f, 0.f, 0.f, 0.f};
#pragma unroll
    for (int ds = 0; ds < 2; ++ds) {
      int ca = ds ? cx2 : cx0, cb = ds ? cx3 : cx1;
#pragma unroll
      for (int ksub = 0; ksub < 4; ++ksub) {
        int base = (ksub * 16 + lq) * 64;
        ushort4 a0 = *(const ushort4*)(Kh + base + ca);
        ushort4 a1 = *(const ushort4*)(Kh + base + cb);
        ushort4 b0 = *(const ushort4*)(Kl + base + ca);
        ushort4 b1 = *(const ushort4*)(Kl + base + cb);
        bf16x8 kh = {(short)a0.x, (short)a0.y, (short)a0.z, (short)a0.w,
                     (short)a1.x, (short)a1.y, (short)a1.z, (short)a1.w};
        bf16x8 kl = {(short)b0.x, (short)b0.y, (short)b0.z, (short)b0.w,
                     (short)b1.x, (short)b1.y, (short)b1.z, (short)b1.w};
#pragma unroll
        for (int qs = 0; qs < 2; ++qs) {
          S[ksub][qs] = __builtin_amdgcn_mfma_f32_16x16x32_bf16(kh, qh[qs][ds], S[ksub][qs], 0, 0, 0);
          S[ksub][qs] = __builtin_amdgcn_mfma_f32_16x16x32_bf16(kh, qlo[qs][ds], S[ksub][qs], 0, 0, 0);
          S[ksub][qs] = __builtin_amdgcn_mfma_f32_16x16x32_bf16(kl, qh[qs][ds], S[ksub][qs], 0, 0, 0);
        }
      }
    }

    // --- online softmax (stats lane-local at lq = q) ---
    bf16x8 pfh[2][2];
    float scl[2];
#pragma unroll
    for (int qs = 0; qs < 2; ++qs) {
      float tmax = -3.0e38f;
#pragma unroll
      for (int ks = 0; ks < 4; ++ks)
#pragma unroll
        for (int r = 0; r < 4; ++r) tmax = fmaxf(tmax, S[ks][qs][r]);
      tmax = fmaxf(tmax, __shfl_xor(tmax, 16, 64));
      tmax = fmaxf(tmax, __shfl_xor(tmax, 32, 64));
      float mn = fmaxf(m_[qs], tmax);
      scl[qs] = __expf(m_[qs] - mn);
      float p[4][4]; float rs = 0.f;
#pragma unroll
      for (int ks = 0; ks < 4; ++ks)
#pragma unroll
        for (int r = 0; r < 4; ++r) {
          float pv = __expf(S[ks][qs][r] - mn);
          p[ks][r] = pv; rs += pv;
        }
      rs += __shfl_xor(rs, 16, 64);
      rs += __shfl_xor(rs, 32, 64);
      l_[qs] = l_[qs] * scl[qs] + rs;
      m_[qs] = mn;
#pragma unroll
      for (int kst = 0; kst < 2; ++kst) {
        bf16x8 h;
#pragma unroll
        for (int jh = 0; jh < 2; ++jh)
#pragma unroll
          for (int j2 = 0; j2 < 4; ++j2)
            h[jh * 4 + j2] = (short)f2bf(p[jh + 2 * kst][j2]);
        pfh[qs][kst] = h;
      }
      // rescale O (cols = q = lq, lane-local)
#pragma unroll
      for (int d2 = 0; d2 < 4; ++d2)
#pragma unroll
        for (int r = 0; r < 4; ++r) O_[qs][d2][r] *= scl[qs];
    }

    // --- O^T += V^T * P^T ---
#pragma unroll
    for (int kst = 0; kst < 2; ++kst) {
      int ca = kst ? cx2 : cx0, cb = kst ? cx3 : cx1;
#pragma unroll
      for (int d2 = 0; d2 < 4; ++d2) {
        int base = (d2 * 16 + lq) * 64;
        ushort4 a0 = *(const ushort4*)(Vh + base + ca);
        ushort4 a1 = *(const ushort4*)(Vh + base + cb);
        ushort4 b0 = *(const ushort4*)(Vl + base + ca);
        ushort4 b1 = *(const ushort4*)(Vl + base + cb);
        bf16x8 vh = {(short)a0.x, (short)a0.y, (short)a0.z, (short)a0.w,
                     (short)a1.x, (short)a1.y, (short)a1.z, (short)a1.w};
        bf16x8 vl = {(short)b0.x, (short)b0.y, (short)b0.z, (short)b0.w,
                     (short)b1.x, (short)b1.y, (short)b1.z, (short)b1.w};
#pragma unroll
        for (int qs = 0; qs < 2; ++qs) {
          O_[qs][d2] = __builtin_amdgcn_mfma_f32_16x16x32_bf16(vh, pfh[qs][kst], O_[qs][d2], 0, 0, 0);
          O_[qs][d2] = __builtin_amdgcn_mfma_f32_16x16x32_bf16(vl, pfh[qs][kst], O_[qs][d2], 0, 0, 0);
        }
      }
    }

    if (!VPREP && kt < 15) VWRITE(cur ^ 1);
    __syncthreads();  // compiler drains vmcnt/lgkm before s_barrier
    cur ^= 1;
  }

  // --- epilogue: O^T rows = d (4g+r contiguous), cols = q = lq ---
  float* Ob = Out + ((size_t)bh * L + q0 + w * 32) * D;
#pragma unroll
  for (int qs = 0; qs < 2; ++qs) {
    float il = 1.f / l_[qs];
    int q = qs * 16 + lq;
#pragma unroll
    for (int d2 = 0; d2 < 4; ++d2) {
      float4 o4;
      o4.x = O_[qs][d2][0] * il; o4.y = O_[qs][d2][1] * il;
      o4.z = O_[qs][d2][2] * il; o4.w = O_[qs][d2][3] * il;
      *(float4*)(Ob + q * D + d2 * 16 + 4 * g) = o4;
    }
  }
#undef STAGE
#undef VLOAD
#undef VWRITE
}

// ---------------- Kernel 6: finalize loss ----------------
__global__ void k_final(const double* __restrict__ dsc, float* __restrict__ out) {
  out[4194304] = (float)(-dsc[0] / 40960.0 - dsc[1] / 40.0);
}

extern "C" void kernel_launch(void* const* d_in, const int* in_sizes, int n_in,
                              void* d_out, int out_size, void* d_ws, size_t ws_size,
                              hipStream_t stream) {
  const float* Q   = (const float*)d_in[0];
  const float* K   = (const float*)d_in[1];
  const float* V   = (const float*)d_in[2];
  const float* wpk = (const float*)d_in[3];
  const float* bpk = (const float*)d_in[4];
  const float* wpb = (const float*)d_in[5];
  const float* bpb = (const float*)d_in[6];
  const float* wck = (const float*)d_in[7];
  const float* bck = (const float*)d_in[8];
  const float* wcq = (const float*)d_in[9];
  const float* bcq = (const float*)d_in[10];
  float* out = (float*)d_out;
  float* ws = (float*)d_ws;
  float* G    = ws + WS_G;
  float* mu   = ws + WS_MU;
  float* q2   = ws + WS_Q2;
  double* dsc = (double*)((char*)d_ws + WS_DSC_BYTE);
  ushort* Khi = (ushort*)((char*)d_ws + WS_KHI_BYTE);
  ushort* Klo = (ushort*)((char*)d_ws + WS_KLO_BYTE);
  ushort* Vthi = (ushort*)((char*)d_ws + WS_VTHI_BYTE);
  ushort* Vtlo = (ushort*)((char*)d_ws + WS_VTLO_BYTE);
  const bool vprep = (ws_size >= (size_t)WS_V_END);  // ws_size constant per session

  hipMemsetAsync((char*)d_ws + WS_DSC_BYTE, 0, 16, stream);
  if (vprep) k_vprep<<<1024, 256, 0, stream>>>(V, Vthi, Vtlo);
  k_part<<<dim3(16, 7), 256, 0, stream>>>(K, wpk, G);
  k_chain<<<32, 256, 0, stream>>>(G, bpk, wck, bck, wcq, bcq, mu, q2, dsc);
  k_ce<<<40, 256, 0, stream>>>(mu, dsc);
  k_kprep<<<16384, 256, 0, stream>>>(q2, wpb, bpb, Khi, Klo);
  if (vprep) {
    k_attn<true><<<512, 256, 0, stream>>>(Q, Khi, Klo, Vthi, Vtlo, V, out);
  } else {
    k_attn<false><<<512, 256, 0, stream>>>(Q, Khi, Klo, nullptr, nullptr, V, out);
  }
  k_final<<<1, 1, 0, stream>>>(dsc, out);
}

// Round 6
// 293.581 us; speedup vs baseline: 1.8733x; 1.0487x over previous
//
#include <hip/hip_runtime.h>
#include <math.h>

#define L 1024
#define D 64
#define H 8
#define B 8

// ---------------- ws layout ----------------
// floats:
#define WS_G     0            // 7*1024*15 = 107520
#define WS_MU    107520       // 8*1024*5  = 40960
#define WS_Q2T   148480       // 8*35*1024 = 286720 (ends 435200 floats)
// bytes:
#define WS_Q2T_BYTE   593920u
#define WS_DSC_BYTE   1740800u   // 2 doubles (right after q2t; one memset covers both)
#define WS_KHI_BYTE   1740816u   // 8,388,608 B (64bh*16kt*4096 ushort)
#define WS_KLO_BYTE   10129424u  // ends 18518032 < 20.2MB known-safe
#define WS_VTHI_BYTE  18518032u
#define WS_VTLO_BYTE  26906640u
#define WS_V_END      35295248u

typedef __attribute__((ext_vector_type(8))) short bf16x8;
typedef __attribute__((ext_vector_type(4))) float f32x4;

__device__ __forceinline__ ushort f2bf(float x) {
  unsigned b = __builtin_bit_cast(unsigned, x);
  return (ushort)((b + 0x7FFFu + ((b >> 16) & 1u)) >> 16);
}
__device__ __forceinline__ float bf2f(ushort u) {
  unsigned t = ((unsigned)u) << 16;
  return __builtin_bit_cast(float, t);
}

// ---------------- Kernel 1: conv1 partials (jj-collapsed) ----------------
__global__ __launch_bounds__(256) void k_part(const float* __restrict__ K,
                                              const float* __restrict__ wpk,
                                              float* __restrict__ G) {
  const int tid = threadIdx.x, lane = tid & 63, wid = tid >> 6;
  const int lq = blockIdx.x;        // 0..15
  const int bip = blockIdx.y + 1;   // 1..7
  __shared__ float w_s[512 * 16];
  __shared__ float red[3][64][16];
  for (int i = tid; i < 512 * 16; i += 256) {
    int c = i >> 4, f = i & 15;
    w_s[i] = (f < 15) ? wpk[((f / 3) * 512 + c) * 3 + (f % 3)] : 0.f;
  }
  __syncthreads();
  float acc[15];
#pragma unroll
  for (int f = 0; f < 15; ++f) acc[f] = 0.f;
  const float* Kb = K + (size_t)bip * (H * L * D);
  const int c0 = wid * 128;
#pragma unroll 4
  for (int c = c0; c < c0 + 128; ++c) {
    float val = Kb[((c >> 6) * L + ((c & 63) << 4) + lq) * D + lane];
    const float4* wr = (const float4*)&w_s[c * 16];
    float4 w0 = wr[0], w1 = wr[1], w2 = wr[2], w3 = wr[3];
    acc[0] = fmaf(val, w0.x, acc[0]);  acc[1] = fmaf(val, w0.y, acc[1]);
    acc[2] = fmaf(val, w0.z, acc[2]);  acc[3] = fmaf(val, w0.w, acc[3]);
    acc[4] = fmaf(val, w1.x, acc[4]);  acc[5] = fmaf(val, w1.y, acc[5]);
    acc[6] = fmaf(val, w1.z, acc[6]);  acc[7] = fmaf(val, w1.w, acc[7]);
    acc[8] = fmaf(val, w2.x, acc[8]);  acc[9] = fmaf(val, w2.y, acc[9]);
    acc[10] = fmaf(val, w2.z, acc[10]); acc[11] = fmaf(val, w2.w, acc[11]);
    acc[12] = fmaf(val, w3.x, acc[12]); acc[13] = fmaf(val, w3.y, acc[13]);
    acc[14] = fmaf(val, w3.z, acc[14]);
  }
  if (wid) {
#pragma unroll
    for (int f = 0; f < 15; ++f) red[wid - 1][lane][f] = acc[f];
  }
  __syncthreads();
  if (wid == 0) {
#pragma unroll
    for (int f = 0; f < 15; ++f)
      acc[f] += red[0][lane][f] + red[1][lane][f] + red[2][lane][f];
    float* dst = G + ((size_t)blockIdx.y * 1024 + (lq << 6) + lane) * 15;
#pragma unroll
    for (int f = 0; f < 15; ++f) dst[f] = acc[f];
  }
}

// ---------------- Kernel 2: per-(bi,li) chain ----------------
// q2t layout: [bi][tap=w1*5+c][li]  (w1 = w+1, taps 0..4 and 30..34 stay zero)
__global__ __launch_bounds__(256) void k_chain(const float* __restrict__ G,
    const float* __restrict__ b_pk, const float* __restrict__ w_ck,
    const float* __restrict__ b_ck, const float* __restrict__ w_cq,
    const float* __restrict__ b_cq, float* __restrict__ mu_out,
    float* __restrict__ q2t, double* __restrict__ dsc) {
  int g = blockIdx.x * 256 + threadIdx.x;  // bi*1024+li
  int bi = g >> 10, li = g & 1023;
  float ckp[5][5];
#pragma unroll
  for (int j = 0; j < 5; ++j) {
#pragma unroll
    for (int nc = 0; nc < 5; ++nc) {
      float s = b_pk[nc];
#pragma unroll
      for (int t = 0; t < 3; ++t) {
        int w = j + t - 1;
        int bip = bi + w - 4;
        if (w >= 0 && w < 5 && bip >= 1)
          s += G[(size_t)((bip - 1) * 1024 + li) * 15 + nc * 3 + t];
      }
      ckp[j][nc] = fmaxf(s, 0.f);
    }
  }
  float cq[5][5], ck[5][5];
  float lp_sum = 0.f;
#pragma unroll
  for (int j = 0; j < 5; ++j) {
    float vk[5], vq[5];
#pragma unroll
    for (int m = 0; m < 5; ++m) {
      float sk = b_ck[m], sq = b_cq[m];
#pragma unroll
      for (int n = 0; n < 5; ++n) {
        sk = fmaf(ckp[j][n], w_ck[m * 5 + n], sk);
        sq = fmaf(ckp[j][n], w_cq[m * 5 + n], sq);
      }
      vk[m] = sk; vq[m] = sq;
    }
    float mk = vk[0], mq = vq[0];
#pragma unroll
    for (int m = 1; m < 5; ++m) { mk = fmaxf(mk, vk[m]); mq = fmaxf(mq, vq[m]); }
    float sk = 0.f, sq = 0.f;
#pragma unroll
    for (int m = 0; m < 5; ++m) {
      vk[m] = expf(vk[m] - mk); sk += vk[m];
      vq[m] = expf(vq[m] - mq); sq += vq[m];
    }
    float rk = 1.f / sk, rq = 1.f / sq;
    float mu = 0.f, x = 0.f;
#pragma unroll
    for (int m = 0; m < 5; ++m) {
      ck[j][m] = vk[m] * rk; cq[j][m] = vq[m] * rq;
      mu += cq[j][m]; x += ck[j][m];
    }
    mu *= 0.2f; x *= 0.2f;
    float var = 0.f;
#pragma unroll
    for (int m = 0; m < 5; ++m) { float d0 = cq[j][m] - mu; var += d0 * d0; }
    var *= 0.25f;
    float sg = log1pf(expf(sqrtf(var)));
    float z = (x - mu) / sg;
    lp_sum += -0.5f * z * z - logf(sg) - 0.91893853320467274f;
    mu_out[(size_t)g * 5 + j] = mu;
  }
  // masked triangular cluster attention -> q2 (written transposed into q2t)
  float* q2p = q2t + (((size_t)bi * 35) << 10) + li;
#pragma unroll
  for (int pp = 0; pp < 5; ++pp) {
    float sc[5]; float mx = -3.0e38f;
    for (int u2 = 0; u2 <= pp; ++u2) {
      float d0 = 0.f;
#pragma unroll
      for (int c = 0; c < 5; ++c) d0 = fmaf(cq[pp][c], ck[u2][c], d0);
      sc[u2] = d0 * 0.2f;
      mx = fmaxf(mx, sc[u2]);
    }
    float den = 0.f;
    for (int u2 = 0; u2 <= pp; ++u2) { sc[u2] = expf(sc[u2] - mx); den += sc[u2]; }
    float rd = 1.f / den;
    float q2v[5] = {0.f, 0.f, 0.f, 0.f, 0.f};
    for (int u2 = 0; u2 <= pp; ++u2) {
      float a = sc[u2] * rd;
#pragma unroll
      for (int c = 0; c < 5; ++c) q2v[c] = fmaf(a, cq[u2][c], q2v[c]);
    }
#pragma unroll
    for (int c = 0; c < 5; ++c) q2p[(size_t)(((pp + 1) * 5 + c)) << 10] = q2v[c];
  }
  for (int off = 1; off < 64; off <<= 1) lp_sum += __shfl_xor(lp_sum, off, 64);
  __shared__ float wsum[4];
  int tid = threadIdx.x;
  if ((tid & 63) == 0) wsum[tid >> 6] = lp_sum;
  __syncthreads();
  if (tid == 0) atomicAdd(dsc, (double)(wsum[0] + wsum[1] + wsum[2] + wsum[3]));
}

// ---------------- Kernel 3: CE over l axis ----------------
__global__ __launch_bounds__(256) void k_ce(const float* __restrict__ mu,
                                            double* __restrict__ dsc) {
  int bi = blockIdx.x / 5, u = blockIdx.x % 5;
  int tid = threadIdx.x;
  const float* base = mu + (size_t)bi * L * 5 + u;
  float v[4];
#pragma unroll
  for (int k = 0; k < 4; ++k) v[k] = base[(tid + 256 * k) * 5];
  float mx = fmaxf(fmaxf(v[0], v[1]), fmaxf(v[2], v[3]));
  for (int off = 1; off < 64; off <<= 1) mx = fmaxf(mx, __shfl_xor(mx, off, 64));
  __shared__ float sh[4];
  if ((tid & 63) == 0) sh[tid >> 6] = mx;
  __syncthreads();
  mx = fmaxf(fmaxf(sh[0], sh[1]), fmaxf(sh[2], sh[3]));
  __syncthreads();
  float se = 0.f;
#pragma unroll
  for (int k = 0; k < 4; ++k) se += expf(v[k] - mx);
  for (int off = 1; off < 64; off <<= 1) se += __shfl_xor(se, off, 64);
  if ((tid & 63) == 0) sh[tid >> 6] = se;
  __syncthreads();
  float lse = mx + logf(sh[0] + sh[1] + sh[2] + sh[3]);
  __syncthreads();
  float part = 0.f;
#pragma unroll
  for (int k = 0; k < 4; ++k) part += v[k] * (v[k] - lse);
  for (int off = 1; off < 64; off <<= 1) part += __shfl_xor(part, off, 64);
  if ((tid & 63) == 0) sh[tid >> 6] = part;
  __syncthreads();
  if (tid == 0) atomicAdd(dsc + 1, (double)(sh[0] + sh[1] + sh[2] + sh[3]));
}

// ---------------- Kernel 4: conv_back in natural order, scatter-add to Keff ----------------
// thread = (co, li2); computes ccfull[bi][co][li2][j] for j=0..4 (75 FMA from
// coalesced q2t taps); LDS repack -> lane-contiguous coalesced atomicAdd.
__global__ __launch_bounds__(256) void k_cback(const float* __restrict__ q2t,
    const float* __restrict__ wb, const float* __restrict__ bb,
    float* __restrict__ keff) {
  __shared__ float ls[1280];
  const int id = blockIdx.x;           // 8 bi * 128 cog * 16 lt
  const int bi = id >> 11, cog = (id >> 4) & 127, lt = id & 15;
  const int tid = threadIdx.x, w = tid >> 6, lane = tid & 63;
  const int co = cog * 4 + w;
  const int li2 = (lt << 6) + lane;
  const float* xb = q2t + (((size_t)bi * 35) << 10) + li2;
  float xt[35];
#pragma unroll
  for (int k = 0; k < 35; ++k) xt[k] = xb[(size_t)k << 10];
  float wbl[15];
#pragma unroll
  for (int t = 0; t < 3; ++t)
#pragma unroll
    for (int c = 0; c < 5; ++c) wbl[t * 5 + c] = wb[co * 15 + c * 3 + t];
  const float bias = bb[co];
#pragma unroll
  for (int j = 0; j < 5; ++j) {
    float s = bias;
#pragma unroll
    for (int i = 0; i < 15; ++i) s = fmaf(xt[j * 5 + i], wbl[i], s);
    ls[w * 320 + lane * 5 + j] = fmaxf(s, 0.f);
  }
  __syncthreads();
  const int base_lo = (cog * 4) * 5120 + (lt << 6) * 5;
#pragma unroll
  for (int k = 0; k < 5; ++k) {
    int e = tid + (k << 8);
    float val = ls[e];
    int we = (int)((unsigned)e / 320u);
    int off = e - we * 320;
    int flat = base_lo + we * 5120 + off;
    int q = flat >> 16;               // hh*5+cc, in [0,40)
    int hh = (q * 205) >> 10;         // q/5
    int idx = (((bi << 3) + hh) << 16) + (flat & 65535);
    atomicAdd(&keff[idx], val);
  }
}

// ---------------- Kernel 4c: Keff f32 -> bf16 hi/lo swizzled tile images ----------------
__global__ __launch_bounds__(256) void k_kfold(const float* __restrict__ keff,
    ushort* __restrict__ Khi_g, ushort* __restrict__ Klo_g) {
  int g = blockIdx.x * 256 + threadIdx.x;   // bi*8+hh | li | dd  (linear)
  float sum = keff[g];
  int li = (g >> 6) & 1023, dd = g & 63;
  int bh = g >> 16;
  int kt = li >> 6, key = li & 63, c = dd >> 2, e = dd & 3;
  int idx = ((bh * 16 + kt) << 12) + (key << 6) + ((c ^ (key & 15)) << 2) + e;
  ushort hb = f2bf(sum);
  Khi_g[idx] = hb;
  Klo_g[idx] = f2bf(sum - bf2f(hb));
}

// ---------------- Kernel 4b: V -> transposed bf16 hi/lo tile image ----------------
__global__ __launch_bounds__(256) void k_vprep(const float* __restrict__ V,
    ushort* __restrict__ Vthi_g, ushort* __restrict__ Vtlo_g) {
  __shared__ float t[64][65];
  const int tile = blockIdx.x;  // bh*16+kt
  const float* Vb = V + ((size_t)tile << 12);
  const int tid = threadIdx.x;
  {
    int key = tid >> 2, c0 = (tid & 3) << 4;
#pragma unroll
    for (int i = 0; i < 4; ++i) {
      float4 v = *(const float4*)(Vb + key * 64 + c0 + 4 * i);
      t[key][c0 + 4 * i + 0] = v.x; t[key][c0 + 4 * i + 1] = v.y;
      t[key][c0 + 4 * i + 2] = v.z; t[key][c0 + 4 * i + 3] = v.w;
    }
  }
  __syncthreads();
  int d = tid >> 2, q4 = tid & 3;
#pragma unroll
  for (int q = 0; q < 4; ++q) {
    int kc = q4 * 4 + q;
    ushort hv[4], lv[4];
#pragma unroll
    for (int e = 0; e < 4; ++e) {
      float x = t[kc * 4 + e][d];
      ushort hb = f2bf(x);
      hv[e] = hb;
      lv[e] = f2bf(x - bf2f(hb));
    }
    int idx = (tile << 12) + (d << 6) + ((kc ^ (d & 15)) << 2);
    ushort4 h4; h4.x = hv[0]; h4.y = hv[1]; h4.z = hv[2]; h4.w = hv[3];
    ushort4 l4; l4.x = lv[0]; l4.y = lv[1]; l4.z = lv[2]; l4.w = lv[3];
    *(ushort4*)(&Vthi_g[idx]) = h4;
    *(ushort4*)(&Vtlo_g[idx]) = l4;
  }
}

// ---------------- Kernel 5: MFMA flash attention (unchanged from R5) ----------------
template<bool VPREP>
__global__ __launch_bounds__(256) void k_attn(const float* __restrict__ Q,
    const ushort* __restrict__ Khi_g, const ushort* __restrict__ Klo_g,
    const ushort* __restrict__ Vthi_g, const ushort* __restrict__ Vtlo_g,
    const float* __restrict__ V, float* __restrict__ Out) {
  __shared__ ushort smem[2][16384];  // [buf][Khi 4K | Klo 4K | Vthi 4K | Vtlo 4K]
  const int tid = threadIdx.x;
  const int lane = tid & 63;
  const int w = tid >> 6;
  const int lq = lane & 15;
  const int g = lane >> 4;
  const int id = blockIdx.x;                 // 0..511
  const int bh = ((id & 7) << 3) + (id >> 6);
  const int qb = (id >> 3) & 7;
  const int q0 = qb << 7;
  const float* Qb = Q + ((size_t)bh * L + q0 + w * 32) * D;
  const float* Vb = V + (size_t)bh * L * D;
  const int tb = bh * 16;

  int cx0 = ((g) ^ lq) << 2, cx1 = ((g + 4) ^ lq) << 2;
  int cx2 = ((g + 8) ^ lq) << 2, cx3 = ((g + 12) ^ lq) << 2;

  bf16x8 qh[2][2], qlo[2][2];
#pragma unroll
  for (int qs = 0; qs < 2; ++qs) {
    const float* Qr = Qb + (qs * 16 + lq) * D;
#pragma unroll
    for (int ds = 0; ds < 2; ++ds) {
      float4 x0 = *(const float4*)(Qr + 4 * g + 32 * ds);
      float4 x1 = *(const float4*)(Qr + 4 * g + 16 + 32 * ds);
      float xs[8] = {x0.x, x0.y, x0.z, x0.w, x1.x, x1.y, x1.z, x1.w};
      bf16x8 h, l;
#pragma unroll
      for (int j = 0; j < 8; ++j) {
        ushort hb = f2bf(xs[j]);
        h[j] = (short)hb;
        l[j] = (short)f2bf(xs[j] - bf2f(hb));
      }
      qh[qs][ds] = h; qlo[qs][ds] = l;
    }
  }

  const ushort* warr;
  int wdst;
  if (VPREP) {
    warr = (w == 0) ? Khi_g : (w == 1) ? Klo_g : (w == 2) ? Vthi_g : Vtlo_g;
    wdst = w << 12;
  } else {
    warr = ((w < 2) ? Khi_g : Klo_g);
    wdst = ((w >> 1) << 12) + ((w & 1) << 11);
  }

#define STAGE(buf_, kt_) do {                                                  \
    const ushort* src_ = warr + ((size_t)(tb + (kt_)) << 12) +                 \
                         (VPREP ? 0 : ((w & 1) << 11)) + lane * 8;             \
    ushort* dst_ = &smem[buf_][wdst];                                          \
    _Pragma("unroll")                                                          \
    for (int r_ = 0; r_ < (VPREP ? 8 : 4); ++r_) {                             \
      __builtin_amdgcn_global_load_lds(                                        \
        (const __attribute__((address_space(1))) unsigned int*)(src_ + r_ * 512), \
        (__attribute__((address_space(3))) unsigned int*)(dst_ + r_ * 512 + lane * 8), \
        16, 0, 0);                                                             \
    }                                                                          \
  } while (0)

  float4 vreg[2][2];
  const int kp = tid & 31, dblk = tid >> 5;
#define VLOAD(kt_) do {                                                        \
    const float* Vb2_ = Vb + ((size_t)(kt_) << 12);                            \
    _Pragma("unroll")                                                          \
    for (int kk_ = 0; kk_ < 2; ++kk_)                                          \
      _Pragma("unroll")                                                        \
      for (int i_ = 0; i_ < 2; ++i_)                                           \
        vreg[kk_][i_] = *(const float4*)(Vb2_ + (2 * kp + kk_) * 64 + dblk * 8 + 4 * i_); \
  } while (0)
#define VWRITE(nb_) do {                                                       \
    ushort vh_[2][8], vl_[2][8];                                               \
    _Pragma("unroll")                                                          \
    for (int kk_ = 0; kk_ < 2; ++kk_)                                          \
      _Pragma("unroll")                                                        \
      for (int i_ = 0; i_ < 2; ++i_) {                                         \
        float xs_[4] = {vreg[kk_][i_].x, vreg[kk_][i_].y, vreg[kk_][i_].z, vreg[kk_][i_].w}; \
        _Pragma("unroll")                                                      \
        for (int e_ = 0; e_ < 4; ++e_) {                                       \
          ushort hb_ = f2bf(xs_[e_]);                                          \
          vh_[kk_][4 * i_ + e_] = hb_;                                         \
          vl_[kk_][4 * i_ + e_] = f2bf(xs_[e_] - bf2f(hb_));                   \
        }                                                                      \
      }                                                                        \
    _Pragma("unroll")                                                          \
    for (int dd_ = 0; dd_ < 8; ++dd_) {                                        \
      int d_ = dblk * 8 + dd_;                                                 \
      int idx_ = (d_ << 6) + (((kp >> 1) ^ (d_ & 15)) << 2) + ((kp & 1) << 1); \
      ushort2 ph_; ph_.x = vh_[0][dd_]; ph_.y = vh_[1][dd_];                   \
      ushort2 pl_; pl_.x = vl_[0][dd_]; pl_.y = vl_[1][dd_];                   \
      *(ushort2*)(&smem[nb_][8192 + idx_]) = ph_;                              \
      *(ushort2*)(&smem[nb_][12288 + idx_]) = pl_;                             \
    }                                                                          \
  } while (0)

  f32x4 O_[2][4];
  float m_[2], l_[2];
#pragma unroll
  for (int qs = 0; qs < 2; ++qs) {
    m_[qs] = -3.0e38f; l_[qs] = 0.f;
#pragma unroll
    for (int d2 = 0; d2 < 4; ++d2) O_[qs][d2] = (f32x4){0.f, 0.f, 0.f, 0.f};
  }

  STAGE(0, 0);
  if (!VPREP) { VLOAD(0); VWRITE(0); }
  __syncthreads();

  int cur = 0;
  for (int kt = 0; kt < 16; ++kt) {
    if (kt < 15) {
      STAGE(cur ^ 1, kt + 1);
      if (!VPREP) VLOAD(kt + 1);
    }

    const ushort* Kh = &smem[cur][0];
    const ushort* Kl = &smem[cur][4096];
    const ushort* Vh = &smem[cur][8192];
    const ushort* Vl = &smem[cur][12288];

    f32x4 S[4][2];
#pragma unroll
    for (int ks = 0; ks < 4; ++ks)
#pragma unroll
      for (int qs = 0; qs < 2; ++qs) S[ks][qs] = (f32x4){0.f, 0.f, 0.f, 0.f};
#pragma unroll
    for (int ds = 0; ds < 2; ++ds) {
      int ca = ds ? cx2 : cx0, cb = ds ? cx3 : cx1;
#pragma unroll
      for (int ksub = 0; ksub < 4; ++ksub) {
        int base = (ksub * 16 + lq) * 64;
        ushort4 a0 = *(const ushort4*)(Kh + base + ca);
        ushort4 a1 = *(const ushort4*)(Kh + base + cb);
        ushort4 b0 = *(const ushort4*)(Kl + base + ca);
        ushort4 b1 = *(const ushort4*)(Kl + base + cb);
        bf16x8 kh = {(short)a0.x, (short)a0.y, (short)a0.z, (short)a0.w,
                     (short)a1.x, (short)a1.y, (short)a1.z, (short)a1.w};
        bf16x8 kl = {(short)b0.x, (short)b0.y, (short)b0.z, (short)b0.w,
                     (short)b1.x, (short)b1.y, (short)b1.z, (short)b1.w};
#pragma unroll
        for (int qs = 0; qs < 2; ++qs) {
          S[ksub][qs] = __builtin_amdgcn_mfma_f32_16x16x32_bf16(kh, qh[qs][ds], S[ksub][qs], 0, 0, 0);
          S[ksub][qs] = __builtin_amdgcn_mfma_f32_16x16x32_bf16(kh, qlo[qs][ds], S[ksub][qs], 0, 0, 0);
          S[ksub][qs] = __builtin_amdgcn_mfma_f32_16x16x32_bf16(kl, qh[qs][ds], S[ksub][qs], 0, 0, 0);
        }
      }
    }

    bf16x8 pfh[2][2];
    float scl[2];
#pragma unroll
    for (int qs = 0; qs < 2; ++qs) {
      float tmax = -3.0e38f;
#pragma unroll
      for (int ks = 0; ks < 4; ++ks)
#pragma unroll
        for (int r = 0; r < 4; ++r) tmax = fmaxf(tmax, S[ks][qs][r]);
      tmax = fmaxf(tmax, __shfl_xor(tmax, 16, 64));
      tmax = fmaxf(tmax, __shfl_xor(tmax, 32, 64));
      float mn = fmaxf(m_[qs], tmax);
      scl[qs] = __expf(m_[qs] - mn);
      float p[4][4]; float rs = 0.f;
#pragma unroll
      for (int ks = 0; ks < 4; ++ks)
#pragma unroll
        for (int r = 0; r < 4; ++r) {
          float pv = __expf(S[ks][qs][r] - mn);
          p[ks][r] = pv; rs += pv;
        }
      rs += __shfl_xor(rs, 16, 64);
      rs += __shfl_xor(rs, 32, 64);
      l_[qs] = l_[qs] * scl[qs] + rs;
      m_[qs] = mn;
#pragma unroll
      for (int kst = 0; kst < 2; ++kst) {
        bf16x8 h;
#pragma unroll
        for (int jh = 0; jh < 2; ++jh)
#pragma unroll
          for (int j2 = 0; j2 < 4; ++j2)
            h[jh * 4 + j2] = (short)f2bf(p[jh + 2 * kst][j2]);
        pfh[qs][kst] = h;
      }
#pragma unroll
      for (int d2 = 0; d2 < 4; ++d2)
#pragma unroll
        for (int r = 0; r < 4; ++r) O_[qs][d2][r] *= scl[qs];
    }

#pragma unroll
    for (int kst = 0; kst < 2; ++kst) {
      int ca = kst ? cx2 : cx0, cb = kst ? cx3 : cx1;
#pragma unroll
      for (int d2 = 0; d2 < 4; ++d2) {
        int base = (d2 * 16 + lq) * 64;
        ushort4 a0 = *(const ushort4*)(Vh + base + ca);
        ushort4 a1 = *(const ushort4*)(Vh + base + cb);
        ushort4 b0 = *(const ushort4*)(Vl + base + ca);
        ushort4 b1 = *(const ushort4*)(Vl + base + cb);
        bf16x8 vh = {(short)a0.x, (short)a0.y, (short)a0.z, (short)a0.w,
                     (short)a1.x, (short)a1.y, (short)a1.z, (short)a1.w};
        bf16x8 vl = {(short)b0.x, (short)b0.y, (short)b0.z, (short)b0.w,
                     (short)b1.x, (short)b1.y, (short)b1.z, (short)b1.w};
#pragma unroll
        for (int qs = 0; qs < 2; ++qs) {
          O_[qs][d2] = __builtin_amdgcn_mfma_f32_16x16x32_bf16(vh, pfh[qs][kst], O_[qs][d2], 0, 0, 0);
          O_[qs][d2] = __builtin_amdgcn_mfma_f32_16x16x32_bf16(vl, pfh[qs][kst], O_[qs][d2], 0, 0, 0);
        }
      }
    }

    if (!VPREP && kt < 15) VWRITE(cur ^ 1);
    __syncthreads();
    cur ^= 1;
  }

  float* Ob = Out + ((size_t)bh * L + q0 + w * 32) * D;
#pragma unroll
  for (int qs = 0; qs < 2; ++qs) {
    float il = 1.f / l_[qs];
    int q = qs * 16 + lq;
#pragma unroll
    for (int d2 = 0; d2 < 4; ++d2) {
      float4 o4;
      o4.x = O_[qs][d2][0] * il; o4.y = O_[qs][d2][1] * il;
      o4.z = O_[qs][d2][2] * il; o4.w = O_[qs][d2][3] * il;
      *(float4*)(Ob + q * D + d2 * 16 + 4 * g) = o4;
    }
  }
#undef STAGE
#undef VLOAD
#undef VWRITE
}

// ---------------- Kernel 6: finalize loss ----------------
__global__ void k_final(const double* __restrict__ dsc, float* __restrict__ out) {
  out[4194304] = (float)(-dsc[0] / 40960.0 - dsc[1] / 40.0);
}

extern "C" void kernel_launch(void* const* d_in, const int* in_sizes, int n_in,
                              void* d_out, int out_size, void* d_ws, size_t ws_size,
                              hipStream_t stream) {
  const float* Q   = (const float*)d_in[0];
  const float* K   = (const float*)d_in[1];
  const float* V   = (const float*)d_in[2];
  const float* wpk = (const float*)d_in[3];
  const float* bpk = (const float*)d_in[4];
  const float* wpb = (const float*)d_in[5];
  const float* bpb = (const float*)d_in[6];
  const float* wck = (const float*)d_in[7];
  const float* bck = (const float*)d_in[8];
  const float* wcq = (const float*)d_in[9];
  const float* bcq = (const float*)d_in[10];
  float* out = (float*)d_out;
  float* ws = (float*)d_ws;
  float* G    = ws + WS_G;
  float* mu   = ws + WS_MU;
  float* q2t  = ws + WS_Q2T;
  double* dsc = (double*)((char*)d_ws + WS_DSC_BYTE);
  ushort* Khi = (ushort*)((char*)d_ws + WS_KHI_BYTE);
  ushort* Klo = (ushort*)((char*)d_ws + WS_KLO_BYTE);
  ushort* Vthi = (ushort*)((char*)d_ws + WS_VTHI_BYTE);
  ushort* Vtlo = (ushort*)((char*)d_ws + WS_VTLO_BYTE);
  const bool vprep = (ws_size >= (size_t)WS_V_END);
  float* keff = out;  // d_out doubles as f32 Keff accumulator (overwritten by attn)

  // zero q2t (incl. halo taps) + dsc in one shot; zero Keff accumulator
  hipMemsetAsync((char*)d_ws + WS_Q2T_BYTE, 0, (WS_DSC_BYTE - WS_Q2T_BYTE) + 16, stream);
  hipMemsetAsync(out, 0, (size_t)4194304 * 4, stream);
  if (vprep) k_vprep<<<1024, 256, 0, stream>>>(V, Vthi, Vtlo);
  k_part<<<dim3(16, 7), 256, 0, stream>>>(K, wpk, G);
  k_chain<<<32, 256, 0, stream>>>(G, bpk, wck, bck, wcq, bcq, mu, q2t, dsc);
  k_ce<<<40, 256, 0, stream>>>(mu, dsc);
  k_cback<<<16384, 256, 0, stream>>>(q2t, wpb, bpb, keff);
  k_kfold<<<16384, 256, 0, stream>>>(keff, Khi, Klo);
  if (vprep) {
    k_attn<true><<<512, 256, 0, stream>>>(Q, Khi, Klo, Vthi, Vtlo, V, out);
  } else {
    k_attn<false><<<512, 256, 0, stream>>>(Q, Khi, Klo, nullptr, nullptr, V, out);
  }
  k_final<<<1, 1, 0, stream>>>(dsc, out);
}